// Round 10
// baseline (6659.685 us; speedup 1.0000x reference)
//
#include <hip/hip_runtime.h>
#include <math.h>

#define B_  32
#define S_  256
#define T_  400
#define M_  80
#define D_  512
#define H_  8
#define DH  64
#define BT  (B_*T_)    // 12800
#define BS  (B_*S_)    // 8192
#define G4  (4*D_)     // 2048
#define DM  (D_+M_)    // 592
#define NB_ 48         // persistent blocks: 16 L0 + 32 L1

typedef short s16x8 __attribute__((ext_vector_type(8)));
typedef float f32x4 __attribute__((ext_vector_type(4)));

__device__ __forceinline__ unsigned short f2bf(float f) {
    union { float f; unsigned u; } v; v.f = f;
    unsigned r = v.u + 0x7fffu + ((v.u >> 16) & 1u);
    return (unsigned short)(r >> 16);
}
__device__ __forceinline__ float us2f(unsigned short u) {
    union { unsigned i; float f; } v; v.i = ((unsigned)u) << 16; return v.f;
}
__device__ __forceinline__ uint4 pack8(const float* f) {
    uint4 u;
    u.x = (unsigned)f2bf(f[0]) | ((unsigned)f2bf(f[1]) << 16);
    u.y = (unsigned)f2bf(f[2]) | ((unsigned)f2bf(f[3]) << 16);
    u.z = (unsigned)f2bf(f[4]) | ((unsigned)f2bf(f[5]) << 16);
    u.w = (unsigned)f2bf(f[6]) | ((unsigned)f2bf(f[7]) << 16);
    return u;
}

// ---------------------------------------------------------------- prep
__global__ __launch_bounds__(256) void k_prep(
    const float* __restrict__ bih0, const float* __restrict__ bhh0,
    const float* __restrict__ bih1, const float* __restrict__ bhh1,
    float* __restrict__ bsum0, float* __restrict__ bsum1,
    int* __restrict__ flags, int* __restrict__ hx2i,
    float* __restrict__ ssum, float* __restrict__ ssq)
{
    int i = blockIdx.x * 256 + threadIdx.x;
    if (i < G4) {
        bsum0[i] = bih0[i] + bhh0[i];
        bsum1[i] = bih1[i] + bhh1[i];
    }
    if (i < 512) { ssum[i] = 0.f; ssq[i] = 0.f; }
    if (i < NB_ * 32) flags[i] = 0;
    if (i < 4 * 32 * 512 / 2) hx2i[i] = 0;   // all 4 hx2 slots
}

// ---------------------------------------------------------------- batched weight prep
__global__ __launch_bounds__(256) void k_w_c4(
    const float* s0, unsigned short* d0p, int n0,
    const float* s1, unsigned short* d1p, int n1,
    const float* s2, unsigned short* d2p, int n2,
    const float* s3, unsigned short* d3p, int n3)
{
    const float* s; unsigned short* d; int n;
    switch (blockIdx.y) {
        case 0: s = s0; d = d0p; n = n0; break;
        case 1: s = s1; d = d1p; n = n1; break;
        case 2: s = s2; d = d2p; n = n2; break;
        default: s = s3; d = d3p; n = n3; break;
    }
    int i = blockIdx.x * 256 + threadIdx.x;
    if (i < n) d[i] = f2bf(s[i]);
}
__global__ __launch_bounds__(256) void k_w_t4(
    const float* s0, unsigned short* d0p, int K0, int N0,
    const float* s1, unsigned short* d1p, int K1, int N1,
    const float* s2, unsigned short* d2p, int K2, int N2,
    const float* s3, unsigned short* d3p, int K3, int N3)
{
    const float* s; unsigned short* d; int K, N;
    switch (blockIdx.y) {
        case 0: s = s0; d = d0p; K = K0; N = N0; break;
        case 1: s = s1; d = d1p; K = K1; N = N1; break;
        case 2: s = s2; d = d2p; K = K2; N = N2; break;
        default: s = s3; d = d3p; K = K3; N = N3; break;
    }
    int i = blockIdx.x * 256 + threadIdx.x;
    if (i < K * N) {
        int n = i / K, k = i - n * K;
        d[i] = f2bf(s[(size_t)k * N + n]);
    }
}
__global__ __launch_bounds__(256) void k_w_conv5(
    const float* s0, unsigned short* d0p, int O0, int C0,
    const float* s1, unsigned short* d1p, int O1, int C1,
    const float* s2, unsigned short* d2p, int O2, int C2,
    const float* s3, unsigned short* d3p, int O3, int C3,
    const float* s4, unsigned short* d4p, int O4, int C4)
{
    const float* s; unsigned short* d; int O, C;
    switch (blockIdx.y) {
        case 0: s = s0; d = d0p; O = O0; C = C0; break;
        case 1: s = s1; d = d1p; O = O1; C = C1; break;
        case 2: s = s2; d = d2p; O = O2; C = C2; break;
        case 3: s = s3; d = d3p; O = O3; C = C3; break;
        default: s = s4; d = d4p; O = O4; C = C4; break;
    }
    int i = blockIdx.x * 256 + threadIdx.x;
    int n = O * C * 5;
    if (i < n) {
        int o = i / (5 * C), rem = i - o * 5 * C;
        int k = rem / C, c = rem - k * C;
        d[i] = f2bf(s[(size_t)o * C * 5 + c * 5 + k]);
    }
}

// ---------------------------------------------------------------- Weff = W_in@Wq, beff = b_in@Wq + bq
__global__ __launch_bounds__(256) void k_weff(
    const float* __restrict__ W_in, const float* __restrict__ Wq,
    const float* __restrict__ b_in, const float* __restrict__ bq,
    float* __restrict__ Weff, float* __restrict__ beff)
{
    int idx = blockIdx.x * 256 + threadIdx.x;
    if (idx < M_ * D_) {
        int m = idx / D_, d = idx - m * D_;
        float acc = 0.f;
        for (int j = 0; j < D_; ++j)
            acc += W_in[(size_t)m * D_ + j] * Wq[(size_t)j * D_ + d];
        Weff[idx] = acc;
    }
    if (idx < D_) {
        float acc = bq[idx];
        for (int j = 0; j < D_; ++j)
            acc += b_in[j] * Wq[(size_t)j * D_ + idx];
        beff[idx] = acc;
    }
}

// ---------------------------------------------------------------- MFMA GEMM (unchanged from R9)
__global__ __launch_bounds__(256) void k_mfma(
    const void* __restrict__ Aptr, int lda, const float* __restrict__ mel, int srcC,
    const unsigned short* __restrict__ Bt,
    void* __restrict__ Cptr, int ldc, const float* __restrict__ bias,
    int M, int N, int K, int mode, int abf16, int cbf16)
{
    __shared__ unsigned short As[128][40];
    __shared__ unsigned short Bs[128][40];
    int tid = threadIdx.x;
    int m0 = blockIdx.x * 128, n0 = blockIdx.y * 128;
    int wave = tid >> 6, lane = tid & 63;
    int wm = (wave >> 1) * 64, wn = (wave & 1) * 64;
    int l15 = lane & 15, quad = lane >> 4;

    f32x4 acc[4][4] = {};

    int srow = tid >> 1, half = tid & 1;
    int arow = m0 + srow;
    bool mok = arow < M;
    int arc = mok ? arow : 0;

    const float* Af = (const float*)Aptr;
    const unsigned short* Ab = (const unsigned short*)Aptr;
    const float* Arow_f = nullptr; const unsigned short* Arow_b = nullptr;
    const float* Mrow = nullptr;
    int bA = 0, tA = 0;
    if (mode == 2) { bA = arc / T_; tA = arc - bA * T_; }
    else {
        if (abf16) Arow_b = Ab + (size_t)arc * lda;
        else       Arow_f = Af + (size_t)arc * lda;
        if (mode == 1) {
            int tt = arc % T_;
            if (tt > 0) Mrow = mel + (size_t)(arc - 1) * M_;
        }
    }
    int brow = n0 + srow;
    bool nok = brow < N;
    const unsigned short* Brow = Bt + (size_t)(nok ? brow : 0) * K;
    const uint4 z4 = make_uint4(0, 0, 0, 0);

    for (int k0 = 0; k0 < K; k0 += 32) {
        int ks = k0 + half * 16;
        uint4 a0, a1;
        if (!mok || ks >= K) { a0 = z4; a1 = z4; }
        else if (mode == 2) {
            int sg = ks / srcC;
            int cc = ks - sg * srcC;
            int tt = tA + sg - 2;
            if (tt >= 0 && tt < T_) {
                float tf[16];
                const float4* s = (const float4*)(Af + (size_t)(bA * T_ + tt) * srcC + cc);
                #pragma unroll
                for (int i = 0; i < 4; ++i) {
                    float4 v = s[i];
                    tf[i*4+0] = v.x; tf[i*4+1] = v.y; tf[i*4+2] = v.z; tf[i*4+3] = v.w;
                }
                a0 = pack8(tf); a1 = pack8(tf + 8);
            } else { a0 = z4; a1 = z4; }
        } else if (abf16) {
            const uint4* s = (const uint4*)(Arow_b + ks);
            a0 = s[0]; a1 = s[1];
        } else if (mode == 1 && ks >= D_) {
            if (Mrow) {
                float tf[16];
                const float4* s = (const float4*)(Mrow + (ks - D_));
                #pragma unroll
                for (int i = 0; i < 4; ++i) {
                    float4 v = s[i];
                    tf[i*4+0] = v.x; tf[i*4+1] = v.y; tf[i*4+2] = v.z; tf[i*4+3] = v.w;
                }
                a0 = pack8(tf); a1 = pack8(tf + 8);
            } else { a0 = z4; a1 = z4; }
        } else {
            float tf[16];
            const float4* s = (const float4*)(Arow_f + ks);
            #pragma unroll
            for (int i = 0; i < 4; ++i) {
                float4 v = s[i];
                tf[i*4+0] = v.x; tf[i*4+1] = v.y; tf[i*4+2] = v.z; tf[i*4+3] = v.w;
            }
            a0 = pack8(tf); a1 = pack8(tf + 8);
        }
        *(uint4*)&As[srow][half * 16]     = a0;
        *(uint4*)&As[srow][half * 16 + 8] = a1;

        uint4 b0, b1;
        if (!nok || ks >= K) { b0 = z4; b1 = z4; }
        else {
            const uint4* s = (const uint4*)(Brow + ks);
            b0 = s[0]; b1 = s[1];
        }
        *(uint4*)&Bs[srow][half * 16]     = b0;
        *(uint4*)&Bs[srow][half * 16 + 8] = b1;
        __syncthreads();

        s16x8 af[4], bfr[4];
        #pragma unroll
        for (int i = 0; i < 4; ++i)
            af[i] = *(const s16x8*)&As[wm + i * 16 + l15][quad * 8];
        #pragma unroll
        for (int j = 0; j < 4; ++j)
            bfr[j] = *(const s16x8*)&Bs[wn + j * 16 + l15][quad * 8];
        #pragma unroll
        for (int i = 0; i < 4; ++i)
            #pragma unroll
            for (int j = 0; j < 4; ++j)
                acc[i][j] = __builtin_amdgcn_mfma_f32_16x16x32_bf16(af[i], bfr[j], acc[i][j], 0, 0, 0);
        __syncthreads();
    }

    #pragma unroll
    for (int i = 0; i < 4; ++i) {
        #pragma unroll
        for (int j = 0; j < 4; ++j) {
            int col = n0 + wn + j * 16 + l15;
            if (col >= N) continue;
            float bv = bias ? bias[col] : 0.f;
            #pragma unroll
            for (int r = 0; r < 4; ++r) {
                int row = m0 + wm + i * 16 + quad * 4 + r;
                if (row >= M) continue;
                float v = acc[i][j][r] + bv;
                if (cbf16) ((unsigned short*)Cptr)[(size_t)row * ldc + col] = f2bf(v);
                else       ((float*)Cptr)[(size_t)row * ldc + col] = v;
            }
        }
    }
}

// ---------------------------------------------------------------- attention (fp32, q on the fly)
__global__ __launch_bounds__(256) void k_attn(
    const float* __restrict__ mel,
    const float* __restrict__ Weff, const float* __restrict__ beff,
    const float* __restrict__ Kb, const float* __restrict__ Vb,
    float* __restrict__ ctx)
{
    __shared__ float mrow[4][80];
    __shared__ float qs[4][64];
    __shared__ float ps[4][256];
    int w = threadIdx.x >> 6, lane = threadIdx.x & 63;
    int row = blockIdx.x * 4 + w;
    int t = row % T_; int bh = row / T_;
    int h = bh % H_;  int b = bh / H_;

    {
        float v = 0.f;
        if (t > 0) v = mel[(size_t)(b * T_ + (t - 1)) * M_ + lane];
        mrow[w][lane] = v;
        if (lane < 16) {
            float v2 = 0.f;
            if (t > 0) v2 = mel[(size_t)(b * T_ + (t - 1)) * M_ + 64 + lane];
            mrow[w][64 + lane] = v2;
        }
    }
    __syncthreads();
    {
        int d = h * DH + lane;
        float q = beff[d];
        #pragma unroll 8
        for (int m = 0; m < M_; ++m) q += mrow[w][m] * Weff[(size_t)m * D_ + d];
        qs[w][lane] = q;
    }
    __syncthreads();

    const float* Kbase = Kb + (size_t)(b * S_) * D_ + h * DH;
    float sc[4];
    #pragma unroll
    for (int i = 0; i < 4; ++i) {
        int s = lane + i * 64;
        const float4* kr = (const float4*)(Kbase + (size_t)s * D_);
        float acc = 0.f;
        #pragma unroll
        for (int c4 = 0; c4 < 16; ++c4) {
            float4 kv = kr[c4];
            acc += qs[w][c4 * 4 + 0] * kv.x + qs[w][c4 * 4 + 1] * kv.y
                 + qs[w][c4 * 4 + 2] * kv.z + qs[w][c4 * 4 + 3] * kv.w;
        }
        sc[i] = acc * 0.125f;
    }
    float mx = fmaxf(fmaxf(sc[0], sc[1]), fmaxf(sc[2], sc[3]));
    #pragma unroll
    for (int off = 32; off; off >>= 1) mx = fmaxf(mx, __shfl_xor(mx, off, 64));
    float sum = 0.f;
    #pragma unroll
    for (int i = 0; i < 4; ++i) { sc[i] = __expf(sc[i] - mx); sum += sc[i]; }
    #pragma unroll
    for (int off = 32; off; off >>= 1) sum += __shfl_xor(sum, off, 64);
    float inv = 1.f / sum;
    #pragma unroll
    for (int i = 0; i < 4; ++i) ps[w][lane + i * 64] = sc[i] * inv;
    __syncthreads();

    const float* Vbase = Vb + (size_t)(b * S_) * D_ + h * DH + lane;
    float acc = 0.f;
    for (int s = 0; s < S_; ++s) acc += ps[w][s] * Vbase[(size_t)s * D_];
    ctx[(size_t)(b * T_ + t) * D_ + h * DH + lane] = acc;
}

// ---------------------------------------------------------------- fused 2-layer LSTM, lagged flag groups
// 48 blocks: bid<16 = L0 (32 dims, K=512); bid>=16 = L1 (16 dims, K=512+512).
// Depth-4 h ping-pong. L0@i waits (L0>=i+1, L1>=i-1); L1@j waits (all>=j+1).
// MFMA B-operands read hx directly from global (L2-resident). LDS row strides % 16B == 0.
__global__ __launch_bounds__(256) void k_lstm2(
    const unsigned short* __restrict__ xg0,   // [B,T,2048] bf16 (bsum0 folded)
    const unsigned short* __restrict__ Whh0,  // [2048,512]
    const unsigned short* __restrict__ Wih1,  // [2048,512]
    const unsigned short* __restrict__ Whh1,  // [2048,512]
    const float* __restrict__ bsum1,          // [2048]
    unsigned short* __restrict__ hx1,         // [4][32*512]
    unsigned short* __restrict__ hx2,         // [4][32*512] (pre-zeroed)
    unsigned short* __restrict__ h2seq,       // [B,T,512]
    int* __restrict__ flags)                  // [48*32]
{
    __shared__ char smem[152064];
    int tid = threadIdx.x;
    int bid = blockIdx.x;
    int lane = tid & 63, wv = tid >> 6;
    int l15 = lane & 15, quad = lane >> 4;

    if (bid < 16) {
        // =========== L0: 32 dims ===========
        unsigned short* Ws   = (unsigned short*)smem;            // [128][520]
        float*          gl   = (float*)(smem + 133120);          // [128][33]
        unsigned short* hout = (unsigned short*)(smem + 150016); // [32][32]
        int d0 = bid * 32;
        {   // Whh0 slice: 128 rows x 512; 2 threads/row
            int r = tid >> 1, half = tid & 1;
            int g = r >> 5, d = r & 31;
            const uint4* src = (const uint4*)(Whh0 + ((size_t)(g * 512 + d0 + d) * 512) + half * 256);
            uint4* dst = (uint4*)(Ws + r * 520 + half * 256);
            #pragma unroll
            for (int j = 0; j < 32; ++j) dst[j] = src[j];
        }
        int b_u = tid & 31, dg = tid >> 5;     // dims dg*4 .. dg*4+3
        float cr[4] = {0.f, 0.f, 0.f, 0.f};
        __syncthreads();

        for (int i = 0; i < 400; ++i) {
            int t = i;
            uint2 xv[4];
            {
                const unsigned short* xr = xg0 + ((size_t)(b_u * T_ + t) * G4) + d0 + dg * 4;
                #pragma unroll
                for (int g = 0; g < 4; ++g) xv[g] = *(const uint2*)(xr + g * 512);
            }
            if (t > 0) {
                const unsigned short* hr = hx1 + ((t - 1) & 3) * (32 * 512);
                int rt0 = 2 * wv, rt1 = 2 * wv + 1;
                f32x4 a00 = {}, a01 = {}, a10 = {}, a11 = {};
                #pragma unroll 4
                for (int k0 = 0; k0 < 512; k0 += 32) {
                    s16x8 b0 = *(const s16x8*)(hr + (size_t)l15 * 512 + k0 + quad * 8);
                    s16x8 b1 = *(const s16x8*)(hr + (size_t)(16 + l15) * 512 + k0 + quad * 8);
                    s16x8 af0 = *(const s16x8*)(Ws + (rt0 * 16 + l15) * 520 + k0 + quad * 8);
                    s16x8 af1 = *(const s16x8*)(Ws + (rt1 * 16 + l15) * 520 + k0 + quad * 8);
                    a00 = __builtin_amdgcn_mfma_f32_16x16x32_bf16(af0, b0, a00, 0, 0, 0);
                    a01 = __builtin_amdgcn_mfma_f32_16x16x32_bf16(af0, b1, a01, 0, 0, 0);
                    a10 = __builtin_amdgcn_mfma_f32_16x16x32_bf16(af1, b0, a10, 0, 0, 0);
                    a11 = __builtin_amdgcn_mfma_f32_16x16x32_bf16(af1, b1, a11, 0, 0, 0);
                }
                #pragma unroll
                for (int r = 0; r < 4; ++r) {
                    gl[(rt0 * 16 + quad * 4 + r) * 33 + l15]      = a00[r];
                    gl[(rt0 * 16 + quad * 4 + r) * 33 + 16 + l15] = a01[r];
                    gl[(rt1 * 16 + quad * 4 + r) * 33 + l15]      = a10[r];
                    gl[(rt1 * 16 + quad * 4 + r) * 33 + 16 + l15] = a11[r];
                }
            }
            __syncthreads();
            {
                unsigned short hb[4];
                #pragma unroll
                for (int q = 0; q < 4; ++q) {
                    int d = dg * 4 + q;
                    float iv = us2f(((const unsigned short*)&xv[0])[q]);
                    float fv = us2f(((const unsigned short*)&xv[1])[q]);
                    float gv = us2f(((const unsigned short*)&xv[2])[q]);
                    float ov = us2f(((const unsigned short*)&xv[3])[q]);
                    if (t > 0) {
                        iv += gl[(0 * 32 + d) * 33 + b_u];
                        fv += gl[(1 * 32 + d) * 33 + b_u];
                        gv += gl[(2 * 32 + d) * 33 + b_u];
                        ov += gl[(3 * 32 + d) * 33 + b_u];
                    }
                    float si = 1.f / (1.f + __expf(-iv));
                    float sf = 1.f / (1.f + __expf(-fv));
                    float so = 1.f / (1.f + __expf(-ov));
                    float tg = tanhf(gv);
                    float c = sf * ((t > 0) ? cr[q] : 0.f) + si * tg;
                    float h = so * tanhf(c);
                    cr[q] = c;
                    hb[q] = f2bf(h);
                }
                *(uint2*)(hout + b_u * 32 + dg * 4) = *(const uint2*)hb;
            }
            __syncthreads();
            if (tid < 128) {
                int b = tid >> 2, seg = tid & 3;
                uint4 v = *(const uint4*)(hout + b * 32 + seg * 8);
                *(uint4*)(hx1 + (t & 3) * (32 * 512) + (size_t)b * 512 + d0 + seg * 8) = v;
            }
            __syncthreads();
            if (tid == 0) {
                __threadfence();
                __hip_atomic_store(flags + bid * 32, i + 1, __ATOMIC_RELEASE, __HIP_MEMORY_SCOPE_AGENT);
            }
            if (i < 399) {
                if (tid < NB_) {
                    int target = (tid < 16) ? (i + 1) : (i - 1);
                    if (target > 0)
                        while (__hip_atomic_load(flags + tid * 32, __ATOMIC_RELAXED, __HIP_MEMORY_SCOPE_AGENT) < target)
                            __builtin_amdgcn_s_sleep(1);
                }
                __syncthreads();
                if (tid == 0) __threadfence();
                __syncthreads();
            }
        }
    } else {
        // =========== L1: 16 dims ===========
        unsigned short* Wc    = (unsigned short*)smem;            // [64][1040]: [Wih1|Whh1]
        float*          gl1   = (float*)(smem + 133120);          // [64][33]
        unsigned short* hout1 = (unsigned short*)(smem + 141568); // [32][16]
        int bd = bid - 16;
        int d0 = bd * 16;
        {   // 64 rows x 1024; 4 threads/row
            int r = tid >> 2, seg = tid & 3;
            int g = r >> 4, d = r & 15;
            const unsigned short* wsrc = ((seg < 2) ? Wih1 : Whh1)
                + (size_t)(g * 512 + d0 + d) * 512 + (seg & 1) * 256;
            uint4* wdst = (uint4*)(Wc + r * 1040 + seg * 256);
            const uint4* ws4 = (const uint4*)wsrc;
            #pragma unroll
            for (int j = 0; j < 32; ++j) wdst[j] = ws4[j];
        }
        int b_u = tid & 31, dg = tid >> 5;     // dims dg*2, dg*2+1
        float cr[2] = {0.f, 0.f};
        float bs[4][2];
        #pragma unroll
        for (int g = 0; g < 4; ++g) {
            bs[g][0] = bsum1[g * 512 + d0 + dg * 2];
            bs[g][1] = bsum1[g * 512 + d0 + dg * 2 + 1];
        }
        __syncthreads();

        for (int j = 0; j < 401; ++j) {
            if (j >= 1) {
                int t = j - 1;
                const unsigned short* h1r = hx1 + (t & 3) * (32 * 512);        // h1[t]
                const unsigned short* h2r = hx2 + ((t + 3) & 3) * (32 * 512);  // h2[t-1]
                f32x4 a0 = {}, a1 = {};
                #pragma unroll 4
                for (int k0 = 0; k0 < 512; k0 += 32) {
                    s16x8 b0 = *(const s16x8*)(h1r + (size_t)l15 * 512 + k0 + quad * 8);
                    s16x8 b1 = *(const s16x8*)(h1r + (size_t)(16 + l15) * 512 + k0 + quad * 8);
                    s16x8 af = *(const s16x8*)(Wc + (wv * 16 + l15) * 1040 + k0 + quad * 8);
                    a0 = __builtin_amdgcn_mfma_f32_16x16x32_bf16(af, b0, a0, 0, 0, 0);
                    a1 = __builtin_amdgcn_mfma_f32_16x16x32_bf16(af, b1, a1, 0, 0, 0);
                }
                if (t > 0) {
                    #pragma unroll 4
                    for (int k0 = 0; k0 < 512; k0 += 32) {
                        s16x8 b0 = *(const s16x8*)(h2r + (size_t)l15 * 512 + k0 + quad * 8);
                        s16x8 b1 = *(const s16x8*)(h2r + (size_t)(16 + l15) * 512 + k0 + quad * 8);
                        s16x8 af = *(const s16x8*)(Wc + (wv * 16 + l15) * 1040 + 512 + k0 + quad * 8);
                        a0 = __builtin_amdgcn_mfma_f32_16x16x32_bf16(af, b0, a0, 0, 0, 0);
                        a1 = __builtin_amdgcn_mfma_f32_16x16x32_bf16(af, b1, a1, 0, 0, 0);
                    }
                }
                #pragma unroll
                for (int r = 0; r < 4; ++r) {
                    gl1[(wv * 16 + quad * 4 + r) * 33 + l15]      = a0[r];
                    gl1[(wv * 16 + quad * 4 + r) * 33 + 16 + l15] = a1[r];
                }
                __syncthreads();
                {
                    unsigned short hb[2];
                    #pragma unroll
                    for (int q = 0; q < 2; ++q) {
                        int d = dg * 2 + q;
                        float iv = gl1[(0 * 16 + d) * 33 + b_u] + bs[0][q];
                        float fv = gl1[(1 * 16 + d) * 33 + b_u] + bs[1][q];
                        float gv = gl1[(2 * 16 + d) * 33 + b_u] + bs[2][q];
                        float ov = gl1[(3 * 16 + d) * 33 + b_u] + bs[3][q];
                        float si = 1.f / (1.f + __expf(-iv));
                        float sf = 1.f / (1.f + __expf(-fv));
                        float so = 1.f / (1.f + __expf(-ov));
                        float tg = tanhf(gv);
                        float c = sf * ((t > 0) ? cr[q] : 0.f) + si * tg;
                        float h = so * tanhf(c);
                        cr[q] = c;
                        hb[q] = f2bf(h);
                    }
                    *(unsigned*)(hout1 + b_u * 16 + dg * 2) = *(const unsigned*)hb;
                }
                __syncthreads();
                if (tid < 64) {
                    int b = tid >> 1, half = tid & 1;
                    uint4 v = *(const uint4*)(hout1 + b * 16 + half * 8);
                    *(uint4*)(hx2 + (t & 3) * (32 * 512) + (size_t)b * 512 + d0 + half * 8) = v;
                    *(uint4*)(h2seq + ((size_t)b * T_ + t) * 512 + d0 + half * 8) = v;
                }
                __syncthreads();
            }
            if (tid == 0) {
                __threadfence();
                __hip_atomic_store(flags + bid * 32, j + 1, __ATOMIC_RELEASE, __HIP_MEMORY_SCOPE_AGENT);
            }
            if (j < 400) {
                if (tid < NB_) {
                    while (__hip_atomic_load(flags + tid * 32, __ATOMIC_RELAXED, __HIP_MEMORY_SCOPE_AGENT) < j + 1)
                        __builtin_amdgcn_s_sleep(1);
                }
                __syncthreads();
                if (tid == 0) __threadfence();
                __syncthreads();
            }
        }
    }
}

// ---------------------------------------------------------------- stop head
__global__ __launch_bounds__(256) void k_stop(
    const unsigned short* __restrict__ h2, const float* __restrict__ W,
    const float* __restrict__ bsc, float* __restrict__ out)
{
    int w = threadIdx.x >> 6, lane = threadIdx.x & 63;
    int row = blockIdx.x * 4 + w;
    const unsigned short* hr = h2 + (size_t)row * 512 + lane * 8;
    float acc = 0.f;
    #pragma unroll
    for (int j = 0; j < 8; ++j) acc += us2f(hr[j]) * W[lane * 8 + j];
    #pragma unroll
    for (int off = 32; off; off >>= 1) acc += __shfl_xor(acc, off, 64);
    if (lane == 0) out[row] = acc + bsc[0];
}

// ---------------------------------------------------------------- BN stats
__global__ __launch_bounds__(256) void k_stats_part(
    const float* __restrict__ x, float* __restrict__ ssum, float* __restrict__ ssq)
{
    int r0 = blockIdx.x * 50;
    int c1 = threadIdx.x, c2 = threadIdx.x + 256;
    float s1 = 0.f, q1 = 0.f, s2 = 0.f, q2 = 0.f;
    for (int r = r0; r < r0 + 50; ++r) {
        float v1 = x[(size_t)r * 512 + c1]; s1 += v1; q1 += v1 * v1;
        float v2 = x[(size_t)r * 512 + c2]; s2 += v2; q2 += v2 * v2;
    }
    atomicAdd(&ssum[c1], s1); atomicAdd(&ssq[c1], q1);
    atomicAdd(&ssum[c2], s2); atomicAdd(&ssq[c2], q2);
}
__global__ __launch_bounds__(256) void k_stats_fin(
    float* __restrict__ ssum, float* __restrict__ ssq,
    const float* __restrict__ gw, const float* __restrict__ bw,
    float* __restrict__ scale, float* __restrict__ shift)
{
    int c = blockIdx.x * 256 + threadIdx.x;
    if (c < 512) {
        float mean = ssum[c] / (float)BT;
        float var  = ssq[c] / (float)BT - mean * mean;
        float scv  = gw[c] * rsqrtf(var + 1e-5f);
        scale[c] = scv;
        shift[c] = bw[c] - mean * scv;
        ssum[c] = 0.f; ssq[c] = 0.f;
    }
}

__global__ __launch_bounds__(256) void k_bnact(
    float* __restrict__ x, int C,
    const float* __restrict__ scale, const float* __restrict__ shift)
{
    int idx = blockIdx.x * 256 + threadIdx.x;
    if (idx < BT * C) {
        int c = idx % C;
        x[idx] = tanhf(scale[c] * x[idx] + shift[c]);
    }
}

__global__ __launch_bounds__(256) void k_residual(
    const float* __restrict__ mel, float* __restrict__ out)
{
    int i = blockIdx.x * 256 + threadIdx.x;
    if (i < BT * M_) out[i] += mel[i];
}

// ================================================================ launch
extern "C" void kernel_launch(void* const* d_in, const int* in_sizes, int n_in,
                              void* d_out, int out_size, void* d_ws, size_t ws_size,
                              hipStream_t stream)
{
    const float* enc    = (const float*)d_in[0];
    const float* mel_t  = (const float*)d_in[1];
    const float* W_in   = (const float*)d_in[2];
    const float* b_in   = (const float*)d_in[3];
    const float* Wq     = (const float*)d_in[4];  const float* bq = (const float*)d_in[5];
    const float* Wk     = (const float*)d_in[6];  const float* bk = (const float*)d_in[7];
    const float* Wv     = (const float*)d_in[8];  const float* bv = (const float*)d_in[9];
    const float* Wo     = (const float*)d_in[10]; const float* bo = (const float*)d_in[11];
    const float* W_ih0  = (const float*)d_in[12]; const float* W_hh0 = (const float*)d_in[13];
    const float* b_ih0  = (const float*)d_in[14]; const float* b_hh0 = (const float*)d_in[15];
    const float* W_ih1  = (const float*)d_in[16]; const float* W_hh1 = (const float*)d_in[17];
    const float* b_ih1  = (const float*)d_in[18]; const float* b_hh1 = (const float*)d_in[19];
    const float* W_mel  = (const float*)d_in[20]; const float* b_mel = (const float*)d_in[21];
    const float* W_stop = (const float*)d_in[22]; const float* b_stop = (const float*)d_in[23];
    const float* pw0 = (const float*)d_in[24]; const float* pb0 = (const float*)d_in[25];
    const float* pw1 = (const float*)d_in[26]; const float* pb1 = (const float*)d_in[27];
    const float* pw2 = (const float*)d_in[28]; const float* pb2 = (const float*)d_in[29];
    const float* pw3 = (const float*)d_in[30]; const float* pb3 = (const float*)d_in[31];
    const float* pw4 = (const float*)d_in[32]; const float* pb4 = (const float*)d_in[33];
    const float* g0 = (const float*)d_in[34]; const float* be0 = (const float*)d_in[35];
    const float* g1 = (const float*)d_in[36]; const float* be1 = (const float*)d_in[37];
    const float* g2 = (const float*)d_in[38]; const float* be2 = (const float*)d_in[39];
    const float* g3 = (const float*)d_in[40]; const float* be3 = (const float*)d_in[41];

    char* p = (char*)d_ws;
    float* Kb  = (float*)(p + 0);
    float* Vb  = (float*)(p + 16777216);
    float* ctx = (float*)(p + 33554432);
    float* ao  = (float*)(p + 0);
    unsigned short* xg0   = (unsigned short*)(p + 26214400);
    unsigned short* h2seq = (unsigned short*)(p + 0);
    float* p_a = (float*)(p + 13107200);
    float* p_b = (float*)(p + 39321600);
    size_t off = 78643200;
    float* bsum0 = (float*)(p + off); off += 8192;
    float* bsum1 = (float*)(p + off); off += 8192;
    unsigned short* hx1 = (unsigned short*)(p + off); off += 131072;
    unsigned short* hx2 = (unsigned short*)(p + off); off += 131072;
    int* flags = (int*)(p + off); off += 6144;
    float* beff = (float*)(p + off); off += 2048;
    float* Weff = (float*)(p + off); off += 163840;
    float* sc0 = (float*)(p + off); off += 2048;
    float* sh0 = (float*)(p + off); off += 2048;
    float* sc1 = (float*)(p + off); off += 2048;
    float* sh1 = (float*)(p + off); off += 2048;
    float* sc2 = (float*)(p + off); off += 2048;
    float* sh2 = (float*)(p + off); off += 2048;
    float* sc3 = (float*)(p + off); off += 2048;
    float* sh3 = (float*)(p + off); off += 2048;
    float* ssum = (float*)(p + off); off += 2048;
    float* ssq  = (float*)(p + off); off += 2048;
    unsigned short* Wk_t   = (unsigned short*)(p + off); off += 524288;
    unsigned short* Wv_t   = (unsigned short*)(p + off); off += 524288;
    unsigned short* Wo_t   = (unsigned short*)(p + off); off += 524288;
    unsigned short* Wmel_t = (unsigned short*)(p + off); off += 81920;
    unsigned short* Wih0_b = (unsigned short*)(p + off); off += 2424832;
    unsigned short* Wih1_b = (unsigned short*)(p + off); off += 2097152;
    unsigned short* Whh0_b = (unsigned short*)(p + off); off += 2097152;
    unsigned short* Whh1_b = (unsigned short*)(p + off); off += 2097152;
    unsigned short* pw0_b  = (unsigned short*)(p + off); off += 409600;
    unsigned short* pw1_b  = (unsigned short*)(p + off); off += 2621440;
    unsigned short* pw2_b  = (unsigned short*)(p + off); off += 2621440;
    unsigned short* pw3_b  = (unsigned short*)(p + off); off += 2621440;
    unsigned short* pw4_b  = (unsigned short*)(p + off); off += 409600;

    float* out_mel  = (float*)d_out;
    float* out_post = out_mel + (size_t)BT * M_;
    float* out_stop = out_post + (size_t)BT * M_;

    dim3 blk(256);
    auto MF = [&](const void* A, int lda, const float* mel, int srcC,
                  const unsigned short* Bt, void* C, int ldc, const float* bias,
                  int M, int N, int K, int mode, int abf16, int cbf16) {
        dim3 g((M + 127) / 128, (N + 127) / 128);
        k_mfma<<<g, blk, 0, stream>>>(A, lda, mel, srcC, Bt, C, ldc, bias, M, N, K, mode, abf16, cbf16);
    };

    // ---- prep
    k_prep<<<128, blk, 0, stream>>>(b_ih0, b_hh0, b_ih1, b_hh1, bsum0, bsum1,
                                    flags, (int*)hx2, ssum, ssq);
    k_weff<<<160, blk, 0, stream>>>(W_in, Wq, b_in, bq, Weff, beff);
    {
        dim3 gc(4736, 4);
        k_w_c4<<<gc, blk, 0, stream>>>(W_ih0, Wih0_b, G4 * DM,
                                       W_ih1, Wih1_b, G4 * D_,
                                       W_hh0, Whh0_b, G4 * D_,
                                       W_hh1, Whh1_b, G4 * D_);
        dim3 gt(1024, 4);
        k_w_t4<<<gt, blk, 0, stream>>>(Wk, Wk_t, D_, D_,
                                       Wv, Wv_t, D_, D_,
                                       Wo, Wo_t, D_, D_,
                                       W_mel, Wmel_t, D_, M_);
        dim3 gv(5120, 5);
        k_w_conv5<<<gv, blk, 0, stream>>>(pw0, pw0_b, 512, 80,
                                          pw1, pw1_b, 512, 512,
                                          pw2, pw2_b, 512, 512,
                                          pw3, pw3_b, 512, 512,
                                          pw4, pw4_b, 80, 512);
    }

    // ---- K/V projections
    MF(enc, D_, nullptr, 0, Wk_t, Kb, D_, bk, BS, D_, D_, 0, 0, 0);
    MF(enc, D_, nullptr, 0, Wv_t, Vb, D_, bv, BS, D_, D_, 0, 0, 0);

    // ---- attention
    k_attn<<<(B_ * H_ * T_) / 4, blk, 0, stream>>>(mel_t, Weff, beff, Kb, Vb, ctx);

    // ---- attn_out = ctx @ Wo + bo
    MF(ctx, D_, nullptr, 0, Wo_t, ao, D_, bo, BT, D_, D_, 0, 0, 0);

    // ---- xg0 (full T, bf16 out, virtual [ao | dec_in] concat, K=592)
    MF(ao, D_, mel_t, 0, Wih0_b, xg0, G4, bsum0, BT, G4, DM, 1, 0, 1);

    // ---- fused 2-layer LSTM with lagged flag groups
    k_lstm2<<<NB_, blk, 0, stream>>>(xg0, Whh0_b, Wih1_b, Whh1_b, bsum1,
                                     hx1, hx2, h2seq, flags);

    // ---- heads
    MF(h2seq, D_, nullptr, 0, Wmel_t, out_mel, M_, b_mel, BT, M_, D_, 0, 1, 0);
    k_stop<<<BT / 4, blk, 0, stream>>>(h2seq, W_stop, b_stop, out_stop);

    // ---- postnet
    int gD = (BT * D_ + 255) / 256;

    MF(out_mel, 0, nullptr, M_, pw0_b, p_a, D_, pb0, BT, D_, M_ * 5, 2, 0, 0);
    k_stats_part<<<256, blk, 0, stream>>>(p_a, ssum, ssq);
    k_stats_fin<<<2, blk, 0, stream>>>(ssum, ssq, g0, be0, sc0, sh0);
    k_bnact<<<gD, blk, 0, stream>>>(p_a, D_, sc0, sh0);

    MF(p_a, 0, nullptr, D_, pw1_b, p_b, D_, pb1, BT, D_, D_ * 5, 2, 0, 0);
    k_stats_part<<<256, blk, 0, stream>>>(p_b, ssum, ssq);
    k_stats_fin<<<2, blk, 0, stream>>>(ssum, ssq, g1, be1, sc1, sh1);
    k_bnact<<<gD, blk, 0, stream>>>(p_b, D_, sc1, sh1);

    MF(p_b, 0, nullptr, D_, pw2_b, p_a, D_, pb2, BT, D_, D_ * 5, 2, 0, 0);
    k_stats_part<<<256, blk, 0, stream>>>(p_a, ssum, ssq);
    k_stats_fin<<<2, blk, 0, stream>>>(ssum, ssq, g2, be2, sc2, sh2);
    k_bnact<<<gD, blk, 0, stream>>>(p_a, D_, sc2, sh2);

    MF(p_a, 0, nullptr, D_, pw3_b, p_b, D_, pb3, BT, D_, D_ * 5, 2, 0, 0);
    k_stats_part<<<256, blk, 0, stream>>>(p_b, ssum, ssq);
    k_stats_fin<<<2, blk, 0, stream>>>(ssum, ssq, g3, be3, sc3, sh3);
    k_bnact<<<gD, blk, 0, stream>>>(p_b, D_, sc3, sh3);

    MF(p_b, 0, nullptr, D_, pw4_b, out_post, M_, pb4, BT, M_, D_ * 5, 2, 0, 0);
    k_residual<<<4000, blk, 0, stream>>>(out_mel, out_post);
}

// Round 11
// 6615.809 us; speedup vs baseline: 1.0066x; 1.0066x over previous
//
#include <hip/hip_runtime.h>
#include <math.h>

#define B_  32
#define S_  256
#define T_  400
#define M_  80
#define D_  512
#define H_  8
#define DH  64
#define BT  (B_*T_)    // 12800
#define BS  (B_*S_)    // 8192
#define G4  (4*D_)     // 2048
#define DM  (D_+M_)    // 592
#define NB_ 96         // persistent blocks: 32 L0 + 64 L1

typedef short s16x8 __attribute__((ext_vector_type(8)));
typedef float f32x4 __attribute__((ext_vector_type(4)));

__device__ __forceinline__ unsigned short f2bf(float f) {
    union { float f; unsigned u; } v; v.f = f;
    unsigned r = v.u + 0x7fffu + ((v.u >> 16) & 1u);
    return (unsigned short)(r >> 16);
}
__device__ __forceinline__ float us2f(unsigned short u) {
    union { unsigned i; float f; } v; v.i = ((unsigned)u) << 16; return v.f;
}
__device__ __forceinline__ uint4 pack8(const float* f) {
    uint4 u;
    u.x = (unsigned)f2bf(f[0]) | ((unsigned)f2bf(f[1]) << 16);
    u.y = (unsigned)f2bf(f[2]) | ((unsigned)f2bf(f[3]) << 16);
    u.z = (unsigned)f2bf(f[4]) | ((unsigned)f2bf(f[5]) << 16);
    u.w = (unsigned)f2bf(f[6]) | ((unsigned)f2bf(f[7]) << 16);
    return u;
}

// ---------------------------------------------------------------- prep
__global__ __launch_bounds__(256) void k_prep(
    const float* __restrict__ bih0, const float* __restrict__ bhh0,
    const float* __restrict__ bih1, const float* __restrict__ bhh1,
    float* __restrict__ bsum0, float* __restrict__ bsum1,
    int* __restrict__ flags, int* __restrict__ hx2i,
    float* __restrict__ ssum, float* __restrict__ ssq)
{
    int i = blockIdx.x * 256 + threadIdx.x;
    if (i < G4) {
        bsum0[i] = bih0[i] + bhh0[i];
        bsum1[i] = bih1[i] + bhh1[i];
    }
    if (i < 512) { ssum[i] = 0.f; ssq[i] = 0.f; }
    if (i < NB_) flags[i] = 0;               // PACKED: one int per block
    if (i < 2 * 32 * 512 / 2) hx2i[i] = 0;   // both hx2 buffers
}

// ---------------------------------------------------------------- batched weight prep
__global__ __launch_bounds__(256) void k_w_c4(
    const float* s0, unsigned short* d0p, int n0,
    const float* s1, unsigned short* d1p, int n1,
    const float* s2, unsigned short* d2p, int n2,
    const float* s3, unsigned short* d3p, int n3)
{
    const float* s; unsigned short* d; int n;
    switch (blockIdx.y) {
        case 0: s = s0; d = d0p; n = n0; break;
        case 1: s = s1; d = d1p; n = n1; break;
        case 2: s = s2; d = d2p; n = n2; break;
        default: s = s3; d = d3p; n = n3; break;
    }
    int i = blockIdx.x * 256 + threadIdx.x;
    if (i < n) d[i] = f2bf(s[i]);
}
__global__ __launch_bounds__(256) void k_w_t4(
    const float* s0, unsigned short* d0p, int K0, int N0,
    const float* s1, unsigned short* d1p, int K1, int N1,
    const float* s2, unsigned short* d2p, int K2, int N2,
    const float* s3, unsigned short* d3p, int K3, int N3)
{
    const float* s; unsigned short* d; int K, N;
    switch (blockIdx.y) {
        case 0: s = s0; d = d0p; K = K0; N = N0; break;
        case 1: s = s1; d = d1p; K = K1; N = N1; break;
        case 2: s = s2; d = d2p; K = K2; N = N2; break;
        default: s = s3; d = d3p; K = K3; N = N3; break;
    }
    int i = blockIdx.x * 256 + threadIdx.x;
    if (i < K * N) {
        int n = i / K, k = i - n * K;
        d[i] = f2bf(s[(size_t)k * N + n]);
    }
}
__global__ __launch_bounds__(256) void k_w_conv5(
    const float* s0, unsigned short* d0p, int O0, int C0,
    const float* s1, unsigned short* d1p, int O1, int C1,
    const float* s2, unsigned short* d2p, int O2, int C2,
    const float* s3, unsigned short* d3p, int O3, int C3,
    const float* s4, unsigned short* d4p, int O4, int C4)
{
    const float* s; unsigned short* d; int O, C;
    switch (blockIdx.y) {
        case 0: s = s0; d = d0p; O = O0; C = C0; break;
        case 1: s = s1; d = d1p; O = O1; C = C1; break;
        case 2: s = s2; d = d2p; O = O2; C = C2; break;
        case 3: s = s3; d = d3p; O = O3; C = C3; break;
        default: s = s4; d = d4p; O = O4; C = C4; break;
    }
    int i = blockIdx.x * 256 + threadIdx.x;
    int n = O * C * 5;
    if (i < n) {
        int o = i / (5 * C), rem = i - o * 5 * C;
        int k = rem / C, c = rem - k * C;
        d[i] = f2bf(s[(size_t)o * C * 5 + c * 5 + k]);
    }
}

// ---------------------------------------------------------------- Weff = W_in@Wq, beff = b_in@Wq + bq
__global__ __launch_bounds__(256) void k_weff(
    const float* __restrict__ W_in, const float* __restrict__ Wq,
    const float* __restrict__ b_in, const float* __restrict__ bq,
    float* __restrict__ Weff, float* __restrict__ beff)
{
    int idx = blockIdx.x * 256 + threadIdx.x;
    if (idx < M_ * D_) {
        int m = idx / D_, d = idx - m * D_;
        float acc = 0.f;
        for (int j = 0; j < D_; ++j)
            acc += W_in[(size_t)m * D_ + j] * Wq[(size_t)j * D_ + d];
        Weff[idx] = acc;
    }
    if (idx < D_) {
        float acc = bq[idx];
        for (int j = 0; j < D_; ++j)
            acc += b_in[j] * Wq[(size_t)j * D_ + idx];
        beff[idx] = acc;
    }
}

// ---------------------------------------------------------------- MFMA GEMM
__global__ __launch_bounds__(256) void k_mfma(
    const void* __restrict__ Aptr, int lda, const float* __restrict__ mel, int srcC,
    const unsigned short* __restrict__ Bt,
    void* __restrict__ Cptr, int ldc, const float* __restrict__ bias,
    int M, int N, int K, int mode, int abf16, int cbf16)
{
    __shared__ unsigned short As[128][40];
    __shared__ unsigned short Bs[128][40];
    int tid = threadIdx.x;
    int m0 = blockIdx.x * 128, n0 = blockIdx.y * 128;
    int wave = tid >> 6, lane = tid & 63;
    int wm = (wave >> 1) * 64, wn = (wave & 1) * 64;
    int l15 = lane & 15, quad = lane >> 4;

    f32x4 acc[4][4] = {};

    int srow = tid >> 1, half = tid & 1;
    int arow = m0 + srow;
    bool mok = arow < M;
    int arc = mok ? arow : 0;

    const float* Af = (const float*)Aptr;
    const unsigned short* Ab = (const unsigned short*)Aptr;
    const float* Arow_f = nullptr; const unsigned short* Arow_b = nullptr;
    const float* Mrow = nullptr;
    int bA = 0, tA = 0;
    if (mode == 2) { bA = arc / T_; tA = arc - bA * T_; }
    else {
        if (abf16) Arow_b = Ab + (size_t)arc * lda;
        else       Arow_f = Af + (size_t)arc * lda;
        if (mode == 1) {
            int tt = arc % T_;
            if (tt > 0) Mrow = mel + (size_t)(arc - 1) * M_;
        }
    }
    int brow = n0 + srow;
    bool nok = brow < N;
    const unsigned short* Brow = Bt + (size_t)(nok ? brow : 0) * K;
    const uint4 z4 = make_uint4(0, 0, 0, 0);

    for (int k0 = 0; k0 < K; k0 += 32) {
        int ks = k0 + half * 16;
        uint4 a0, a1;
        if (!mok || ks >= K) { a0 = z4; a1 = z4; }
        else if (mode == 2) {
            int sg = ks / srcC;
            int cc = ks - sg * srcC;
            int tt = tA + sg - 2;
            if (tt >= 0 && tt < T_) {
                float tf[16];
                const float4* s = (const float4*)(Af + (size_t)(bA * T_ + tt) * srcC + cc);
                #pragma unroll
                for (int i = 0; i < 4; ++i) {
                    float4 v = s[i];
                    tf[i*4+0] = v.x; tf[i*4+1] = v.y; tf[i*4+2] = v.z; tf[i*4+3] = v.w;
                }
                a0 = pack8(tf); a1 = pack8(tf + 8);
            } else { a0 = z4; a1 = z4; }
        } else if (abf16) {
            const uint4* s = (const uint4*)(Arow_b + ks);
            a0 = s[0]; a1 = s[1];
        } else if (mode == 1 && ks >= D_) {
            if (Mrow) {
                float tf[16];
                const float4* s = (const float4*)(Mrow + (ks - D_));
                #pragma unroll
                for (int i = 0; i < 4; ++i) {
                    float4 v = s[i];
                    tf[i*4+0] = v.x; tf[i*4+1] = v.y; tf[i*4+2] = v.z; tf[i*4+3] = v.w;
                }
                a0 = pack8(tf); a1 = pack8(tf + 8);
            } else { a0 = z4; a1 = z4; }
        } else {
            float tf[16];
            const float4* s = (const float4*)(Arow_f + ks);
            #pragma unroll
            for (int i = 0; i < 4; ++i) {
                float4 v = s[i];
                tf[i*4+0] = v.x; tf[i*4+1] = v.y; tf[i*4+2] = v.z; tf[i*4+3] = v.w;
            }
            a0 = pack8(tf); a1 = pack8(tf + 8);
        }
        *(uint4*)&As[srow][half * 16]     = a0;
        *(uint4*)&As[srow][half * 16 + 8] = a1;

        uint4 b0, b1;
        if (!nok || ks >= K) { b0 = z4; b1 = z4; }
        else {
            const uint4* s = (const uint4*)(Brow + ks);
            b0 = s[0]; b1 = s[1];
        }
        *(uint4*)&Bs[srow][half * 16]     = b0;
        *(uint4*)&Bs[srow][half * 16 + 8] = b1;
        __syncthreads();

        s16x8 af[4], bfr[4];
        #pragma unroll
        for (int i = 0; i < 4; ++i)
            af[i] = *(const s16x8*)&As[wm + i * 16 + l15][quad * 8];
        #pragma unroll
        for (int j = 0; j < 4; ++j)
            bfr[j] = *(const s16x8*)&Bs[wn + j * 16 + l15][quad * 8];
        #pragma unroll
        for (int i = 0; i < 4; ++i)
            #pragma unroll
            for (int j = 0; j < 4; ++j)
                acc[i][j] = __builtin_amdgcn_mfma_f32_16x16x32_bf16(af[i], bfr[j], acc[i][j], 0, 0, 0);
        __syncthreads();
    }

    #pragma unroll
    for (int i = 0; i < 4; ++i) {
        #pragma unroll
        for (int j = 0; j < 4; ++j) {
            int col = n0 + wn + j * 16 + l15;
            if (col >= N) continue;
            float bv = bias ? bias[col] : 0.f;
            #pragma unroll
            for (int r = 0; r < 4; ++r) {
                int row = m0 + wm + i * 16 + quad * 4 + r;
                if (row >= M) continue;
                float v = acc[i][j][r] + bv;
                if (cbf16) ((unsigned short*)Cptr)[(size_t)row * ldc + col] = f2bf(v);
                else       ((float*)Cptr)[(size_t)row * ldc + col] = v;
            }
        }
    }
}

// ---------------------------------------------------------------- attention (fp32, q on the fly)
__global__ __launch_bounds__(256) void k_attn(
    const float* __restrict__ mel,
    const float* __restrict__ Weff, const float* __restrict__ beff,
    const float* __restrict__ Kb, const float* __restrict__ Vb,
    float* __restrict__ ctx)
{
    __shared__ float mrow[4][80];
    __shared__ float qs[4][64];
    __shared__ float ps[4][256];
    int w = threadIdx.x >> 6, lane = threadIdx.x & 63;
    int row = blockIdx.x * 4 + w;
    int t = row % T_; int bh = row / T_;
    int h = bh % H_;  int b = bh / H_;

    {
        float v = 0.f;
        if (t > 0) v = mel[(size_t)(b * T_ + (t - 1)) * M_ + lane];
        mrow[w][lane] = v;
        if (lane < 16) {
            float v2 = 0.f;
            if (t > 0) v2 = mel[(size_t)(b * T_ + (t - 1)) * M_ + 64 + lane];
            mrow[w][64 + lane] = v2;
        }
    }
    __syncthreads();
    {
        int d = h * DH + lane;
        float q = beff[d];
        #pragma unroll 8
        for (int m = 0; m < M_; ++m) q += mrow[w][m] * Weff[(size_t)m * D_ + d];
        qs[w][lane] = q;
    }
    __syncthreads();

    const float* Kbase = Kb + (size_t)(b * S_) * D_ + h * DH;
    float sc[4];
    #pragma unroll
    for (int i = 0; i < 4; ++i) {
        int s = lane + i * 64;
        const float4* kr = (const float4*)(Kbase + (size_t)s * D_);
        float acc = 0.f;
        #pragma unroll
        for (int c4 = 0; c4 < 16; ++c4) {
            float4 kv = kr[c4];
            acc += qs[w][c4 * 4 + 0] * kv.x + qs[w][c4 * 4 + 1] * kv.y
                 + qs[w][c4 * 4 + 2] * kv.z + qs[w][c4 * 4 + 3] * kv.w;
        }
        sc[i] = acc * 0.125f;
    }
    float mx = fmaxf(fmaxf(sc[0], sc[1]), fmaxf(sc[2], sc[3]));
    #pragma unroll
    for (int off = 32; off; off >>= 1) mx = fmaxf(mx, __shfl_xor(mx, off, 64));
    float sum = 0.f;
    #pragma unroll
    for (int i = 0; i < 4; ++i) { sc[i] = __expf(sc[i] - mx); sum += sc[i]; }
    #pragma unroll
    for (int off = 32; off; off >>= 1) sum += __shfl_xor(sum, off, 64);
    float inv = 1.f / sum;
    #pragma unroll
    for (int i = 0; i < 4; ++i) ps[w][lane + i * 64] = sc[i] * inv;
    __syncthreads();

    const float* Vbase = Vb + (size_t)(b * S_) * D_ + h * DH + lane;
    float acc = 0.f;
    for (int s = 0; s < S_; ++s) acc += ps[w][s] * Vbase[(size_t)s * D_];
    ctx[(size_t)(b * T_ + t) * D_ + h * DH + lane] = acc;
}

// ---------------------------------------------------------------- fused 2-layer pipelined LSTM (R9 structure)
// 96 blocks: bid<32 = L0 (16 dims, K=512, xg0 precomputed); bid>=32 = L1 (8 dims, K=1024
// fused [W_ih1|W_hh1]·[h1[t]|h2[t-1]]). Interval i: L0 -> h1[i] (i<400); L1 -> h2[i-1] (i>=1).
// PACKED per-block arrival flags (4B apart -> poll reads 6 lines, was 96).
__global__ __launch_bounds__(256) void k_lstm2(
    const unsigned short* __restrict__ xg0,   // [B,T,2048] bf16 (bsum0 folded)
    const unsigned short* __restrict__ Whh0,  // [2048,512]
    const unsigned short* __restrict__ Wih1,  // [2048,512]
    const unsigned short* __restrict__ Whh1,  // [2048,512]
    const float* __restrict__ bsum1,          // [2048]
    unsigned short* __restrict__ hx1,         // [2][32*512]
    unsigned short* __restrict__ hx2,         // [2][32*512] (pre-zeroed)
    unsigned short* __restrict__ h2seq,       // [B,T,512]
    int* __restrict__ flags)                  // [96] packed
{
    __shared__ char smem[137856];
    int tid = threadIdx.x;
    int bid = blockIdx.x;
    int lane = tid & 63, wv = tid >> 6;
    int l15 = lane & 15, quad = lane >> 4;

    if (bid < 32) {
        // =================== L0: 16 dims ===================
        unsigned short* Ws   = (unsigned short*)smem;              // [64][520]
        unsigned short* hs   = Ws + 64 * 520;                      // [32][520]
        float*          gl   = (float*)(smem + 99840);             // [64][33]
        unsigned short* hout = (unsigned short*)(smem + 108288);   // [32][16]
        int d0 = bid * 16;
        {   // Whh0 slice: 64 rows x 512
            int r = tid >> 2, seg = tid & 3;
            int g = r >> 4, d = r & 15;
            const uint4* src = (const uint4*)(Whh0 + ((size_t)(g * 512 + d0 + d) * 512) + seg * 128);
            uint4* dst = (uint4*)(Ws + r * 520 + seg * 128);
            #pragma unroll
            for (int j = 0; j < 16; ++j) dst[j] = src[j];
        }
        int b_u = tid >> 3, dp = tid & 7;
        float c0r = 0.f, c1r = 0.f;
        __syncthreads();

        for (int i = 0; i <= 400; ++i) {
            if (i < 400) {
                int t = i;
                unsigned xv[4];
                {
                    const unsigned short* xr = xg0 + ((size_t)(b_u * T_ + t) * G4) + d0 + 2 * dp;
                    #pragma unroll
                    for (int g = 0; g < 4; ++g) xv[g] = *(const unsigned*)(xr + g * 512);
                }
                if (t > 0) {
                    const uint4* hrd = (const uint4*)(hx1 + ((t + 1) & 1) * (32 * 512));
                    #pragma unroll
                    for (int it = 0; it < 8; ++it) {
                        int u = it * 256 + tid;
                        int row = u >> 6, c8 = u & 63;
                        *(uint4*)(hs + row * 520 + c8 * 8) = hrd[u];
                    }
                    __syncthreads();
                    f32x4 acc0 = {}, acc1 = {};
                    #pragma unroll
                    for (int k0 = 0; k0 < 512; k0 += 32) {
                        s16x8 af = *(const s16x8*)(Ws + (wv * 16 + l15) * 520 + k0 + quad * 8);
                        s16x8 b0 = *(const s16x8*)(hs + l15 * 520 + k0 + quad * 8);
                        s16x8 b1 = *(const s16x8*)(hs + (16 + l15) * 520 + k0 + quad * 8);
                        acc0 = __builtin_amdgcn_mfma_f32_16x16x32_bf16(af, b0, acc0, 0, 0, 0);
                        acc1 = __builtin_amdgcn_mfma_f32_16x16x32_bf16(af, b1, acc1, 0, 0, 0);
                    }
                    #pragma unroll
                    for (int r = 0; r < 4; ++r) {
                        gl[(wv * 16 + quad * 4 + r) * 33 + l15]      = acc0[r];
                        gl[(wv * 16 + quad * 4 + r) * 33 + 16 + l15] = acc1[r];
                    }
                }
                __syncthreads();
                {
                    float h2v[2];
                    #pragma unroll
                    for (int q = 0; q < 2; ++q) {
                        int d = 2 * dp + q;
                        float iv = us2f((unsigned short)(xv[0] >> (16 * q)));
                        float fv = us2f((unsigned short)(xv[1] >> (16 * q)));
                        float gv = us2f((unsigned short)(xv[2] >> (16 * q)));
                        float ov = us2f((unsigned short)(xv[3] >> (16 * q)));
                        if (t > 0) {
                            iv += gl[(0 * 16 + d) * 33 + b_u];
                            fv += gl[(1 * 16 + d) * 33 + b_u];
                            gv += gl[(2 * 16 + d) * 33 + b_u];
                            ov += gl[(3 * 16 + d) * 33 + b_u];
                        }
                        float si = 1.f / (1.f + __expf(-iv));
                        float sf = 1.f / (1.f + __expf(-fv));
                        float so = 1.f / (1.f + __expf(-ov));
                        float tg = tanhf(gv);
                        float cold = (t > 0) ? (q ? c1r : c0r) : 0.f;
                        float c = sf * cold + si * tg;
                        float h = so * tanhf(c);
                        if (q) c1r = c; else c0r = c;
                        h2v[q] = h;
                    }
                    unsigned pk = (unsigned)f2bf(h2v[0]) | ((unsigned)f2bf(h2v[1]) << 16);
                    *(unsigned*)(hout + b_u * 16 + 2 * dp) = pk;
                }
                __syncthreads();
                if (tid < 64) {
                    int b = tid >> 1, hf = tid & 1;
                    uint4 v = *(const uint4*)(hout + b * 16 + hf * 8);
                    *(uint4*)(hx1 + (t & 1) * (32 * 512) + (size_t)b * 512 + d0 + hf * 8) = v;
                }
            }
            if (i < 400) {
                __syncthreads();
                if (tid == 0) {
                    __threadfence();
                    __hip_atomic_store(flags + bid, i + 1, __ATOMIC_RELEASE, __HIP_MEMORY_SCOPE_AGENT);
                }
                if (tid < NB_) {
                    while (__hip_atomic_load(flags + tid, __ATOMIC_RELAXED, __HIP_MEMORY_SCOPE_AGENT) < i + 1)
                        __builtin_amdgcn_s_sleep(1);
                }
                __syncthreads();
                if (tid == 0) __threadfence();
                __syncthreads();
            }
        }
    } else {
        // =================== L1: 8 dims, fused K=1024 matvec ===================
        unsigned short* Wc    = (unsigned short*)smem;             // [32][1040]
        unsigned short* hcat  = Wc + 32 * 1040;                    // [32][1040]
        float*          gl1   = (float*)(smem + 133120);           // [32][33]
        unsigned short* hout1 = (unsigned short*)(smem + 137344);  // [32][8]
        int bd1 = bid - 32;
        int d0 = bd1 * 8;
        {   // [W_ih1 | W_hh1] slice: 32 rows x 1024
            int r = tid >> 3, seg = tid & 7;
            int g = r >> 3, d = r & 7;
            const unsigned short* wsrc = ((seg < 4) ? Wih1 : Whh1)
                + (size_t)(g * 512 + d0 + d) * 512 + (seg & 3) * 128;
            uint4* wdst = (uint4*)(Wc + r * 1040 + seg * 128);
            const uint4* ws4 = (const uint4*)wsrc;
            #pragma unroll
            for (int j = 0; j < 16; ++j) wdst[j] = ws4[j];
        }
        int dd = tid >> 5, b_u = tid & 31;
        float bs[4];
        #pragma unroll
        for (int g = 0; g < 4; ++g) bs[g] = bsum1[g * 512 + d0 + dd];
        int mt = wv >> 1, nt = wv & 1;
        float creg = 0.f;
        __syncthreads();

        for (int i = 0; i <= 400; ++i) {
            if (i >= 1) {
                int t = i - 1;
                const uint4* s1 = (const uint4*)(hx1 + ((i - 1) & 1) * (32 * 512));
                const uint4* s2 = (const uint4*)(hx2 + ((i - 2) & 1) * (32 * 512));
                #pragma unroll
                for (int it = 0; it < 8; ++it) {
                    int u = it * 256 + tid;
                    int row = u >> 6, c8 = u & 63;
                    *(uint4*)(hcat + row * 1040 + c8 * 8)       = s1[u];
                    *(uint4*)(hcat + row * 1040 + 512 + c8 * 8) = s2[u];
                }
                __syncthreads();
                f32x4 acc = {};
                #pragma unroll 4
                for (int k0 = 0; k0 < 1024; k0 += 32) {
                    s16x8 af = *(const s16x8*)(Wc + (mt * 16 + l15) * 1040 + k0 + quad * 8);
                    s16x8 bf = *(const s16x8*)(hcat + (nt * 16 + l15) * 1040 + k0 + quad * 8);
                    acc = __builtin_amdgcn_mfma_f32_16x16x32_bf16(af, bf, acc, 0, 0, 0);
                }
                #pragma unroll
                for (int r = 0; r < 4; ++r)
                    gl1[(mt * 16 + quad * 4 + r) * 33 + nt * 16 + l15] = acc[r];
                __syncthreads();
                {
                    float iv = gl1[(0 * 8 + dd) * 33 + b_u] + bs[0];
                    float fv = gl1[(1 * 8 + dd) * 33 + b_u] + bs[1];
                    float gv = gl1[(2 * 8 + dd) * 33 + b_u] + bs[2];
                    float ov = gl1[(3 * 8 + dd) * 33 + b_u] + bs[3];
                    float si = 1.f / (1.f + __expf(-iv));
                    float sf = 1.f / (1.f + __expf(-fv));
                    float so = 1.f / (1.f + __expf(-ov));
                    float tg = tanhf(gv);
                    float cold = (t > 0) ? creg : 0.f;
                    float c = sf * cold + si * tg;
                    float h = so * tanhf(c);
                    creg = c;
                    hout1[b_u * 8 + dd] = f2bf(h);
                }
                __syncthreads();
                if (tid < 32) {
                    uint4 v = *(const uint4*)(hout1 + tid * 8);
                    *(uint4*)(hx2 + (t & 1) * (32 * 512) + (size_t)tid * 512 + d0) = v;
                    *(uint4*)(h2seq + ((size_t)tid * T_ + t) * 512 + d0) = v;
                }
            }
            if (i < 400) {
                __syncthreads();
                if (tid == 0) {
                    __threadfence();
                    __hip_atomic_store(flags + bid, i + 1, __ATOMIC_RELEASE, __HIP_MEMORY_SCOPE_AGENT);
                }
                if (tid < NB_) {
                    while (__hip_atomic_load(flags + tid, __ATOMIC_RELAXED, __HIP_MEMORY_SCOPE_AGENT) < i + 1)
                        __builtin_amdgcn_s_sleep(1);
                }
                __syncthreads();
                if (tid == 0) __threadfence();
                __syncthreads();
            }
        }
    }
}

// ---------------------------------------------------------------- stop head
__global__ __launch_bounds__(256) void k_stop(
    const unsigned short* __restrict__ h2, const float* __restrict__ W,
    const float* __restrict__ bsc, float* __restrict__ out)
{
    int w = threadIdx.x >> 6, lane = threadIdx.x & 63;
    int row = blockIdx.x * 4 + w;
    const unsigned short* hr = h2 + (size_t)row * 512 + lane * 8;
    float acc = 0.f;
    #pragma unroll
    for (int j = 0; j < 8; ++j) acc += us2f(hr[j]) * W[lane * 8 + j];
    #pragma unroll
    for (int off = 32; off; off >>= 1) acc += __shfl_xor(acc, off, 64);
    if (lane == 0) out[row] = acc + bsc[0];
}

// ---------------------------------------------------------------- BN stats
__global__ __launch_bounds__(256) void k_stats_part(
    const float* __restrict__ x, float* __restrict__ ssum, float* __restrict__ ssq)
{
    int r0 = blockIdx.x * 50;
    int c1 = threadIdx.x, c2 = threadIdx.x + 256;
    float s1 = 0.f, q1 = 0.f, s2 = 0.f, q2 = 0.f;
    for (int r = r0; r < r0 + 50; ++r) {
        float v1 = x[(size_t)r * 512 + c1]; s1 += v1; q1 += v1 * v1;
        float v2 = x[(size_t)r * 512 + c2]; s2 += v2; q2 += v2 * v2;
    }
    atomicAdd(&ssum[c1], s1); atomicAdd(&ssq[c1], q1);
    atomicAdd(&ssum[c2], s2); atomicAdd(&ssq[c2], q2);
}
__global__ __launch_bounds__(256) void k_stats_fin(
    float* __restrict__ ssum, float* __restrict__ ssq,
    const float* __restrict__ gw, const float* __restrict__ bw,
    float* __restrict__ scale, float* __restrict__ shift)
{
    int c = blockIdx.x * 256 + threadIdx.x;
    if (c < 512) {
        float mean = ssum[c] / (float)BT;
        float var  = ssq[c] / (float)BT - mean * mean;
        float scv  = gw[c] * rsqrtf(var + 1e-5f);
        scale[c] = scv;
        shift[c] = bw[c] - mean * scv;
        ssum[c] = 0.f; ssq[c] = 0.f;
    }
}

__global__ __launch_bounds__(256) void k_bnact(
    float* __restrict__ x, int C,
    const float* __restrict__ scale, const float* __restrict__ shift)
{
    int idx = blockIdx.x * 256 + threadIdx.x;
    if (idx < BT * C) {
        int c = idx % C;
        x[idx] = tanhf(scale[c] * x[idx] + shift[c]);
    }
}

__global__ __launch_bounds__(256) void k_residual(
    const float* __restrict__ mel, float* __restrict__ out)
{
    int i = blockIdx.x * 256 + threadIdx.x;
    if (i < BT * M_) out[i] += mel[i];
}

// ================================================================ launch
extern "C" void kernel_launch(void* const* d_in, const int* in_sizes, int n_in,
                              void* d_out, int out_size, void* d_ws, size_t ws_size,
                              hipStream_t stream)
{
    const float* enc    = (const float*)d_in[0];
    const float* mel_t  = (const float*)d_in[1];
    const float* W_in   = (const float*)d_in[2];
    const float* b_in   = (const float*)d_in[3];
    const float* Wq     = (const float*)d_in[4];  const float* bq = (const float*)d_in[5];
    const float* Wk     = (const float*)d_in[6];  const float* bk = (const float*)d_in[7];
    const float* Wv     = (const float*)d_in[8];  const float* bv = (const float*)d_in[9];
    const float* Wo     = (const float*)d_in[10]; const float* bo = (const float*)d_in[11];
    const float* W_ih0  = (const float*)d_in[12]; const float* W_hh0 = (const float*)d_in[13];
    const float* b_ih0  = (const float*)d_in[14]; const float* b_hh0 = (const float*)d_in[15];
    const float* W_ih1  = (const float*)d_in[16]; const float* W_hh1 = (const float*)d_in[17];
    const float* b_ih1  = (const float*)d_in[18]; const float* b_hh1 = (const float*)d_in[19];
    const float* W_mel  = (const float*)d_in[20]; const float* b_mel = (const float*)d_in[21];
    const float* W_stop = (const float*)d_in[22]; const float* b_stop = (const float*)d_in[23];
    const float* pw0 = (const float*)d_in[24]; const float* pb0 = (const float*)d_in[25];
    const float* pw1 = (const float*)d_in[26]; const float* pb1 = (const float*)d_in[27];
    const float* pw2 = (const float*)d_in[28]; const float* pb2 = (const float*)d_in[29];
    const float* pw3 = (const float*)d_in[30]; const float* pb3 = (const float*)d_in[31];
    const float* pw4 = (const float*)d_in[32]; const float* pb4 = (const float*)d_in[33];
    const float* g0 = (const float*)d_in[34]; const float* be0 = (const float*)d_in[35];
    const float* g1 = (const float*)d_in[36]; const float* be1 = (const float*)d_in[37];
    const float* g2 = (const float*)d_in[38]; const float* be2 = (const float*)d_in[39];
    const float* g3 = (const float*)d_in[40]; const float* be3 = (const float*)d_in[41];

    char* p = (char*)d_ws;
    float* Kb  = (float*)(p + 0);
    float* Vb  = (float*)(p + 16777216);
    float* ctx = (float*)(p + 33554432);
    float* ao  = (float*)(p + 0);
    unsigned short* xg0   = (unsigned short*)(p + 26214400);
    unsigned short* h2seq = (unsigned short*)(p + 0);
    float* p_a = (float*)(p + 13107200);
    float* p_b = (float*)(p + 39321600);
    size_t off = 78643200;
    float* bsum0 = (float*)(p + off); off += 8192;
    float* bsum1 = (float*)(p + off); off += 8192;
    unsigned short* hx1 = (unsigned short*)(p + off); off += 65536;
    unsigned short* hx2 = (unsigned short*)(p + off); off += 65536;
    int* flags = (int*)(p + off); off += 512;
    float* beff = (float*)(p + off); off += 2048;
    float* Weff = (float*)(p + off); off += 163840;
    float* sc0 = (float*)(p + off); off += 2048;
    float* sh0 = (float*)(p + off); off += 2048;
    float* sc1 = (float*)(p + off); off += 2048;
    float* sh1 = (float*)(p + off); off += 2048;
    float* sc2 = (float*)(p + off); off += 2048;
    float* sh2 = (float*)(p + off); off += 2048;
    float* sc3 = (float*)(p + off); off += 2048;
    float* sh3 = (float*)(p + off); off += 2048;
    float* ssum = (float*)(p + off); off += 2048;
    float* ssq  = (float*)(p + off); off += 2048;
    unsigned short* Wk_t   = (unsigned short*)(p + off); off += 524288;
    unsigned short* Wv_t   = (unsigned short*)(p + off); off += 524288;
    unsigned short* Wo_t   = (unsigned short*)(p + off); off += 524288;
    unsigned short* Wmel_t = (unsigned short*)(p + off); off += 81920;
    unsigned short* Wih0_b = (unsigned short*)(p + off); off += 2424832;
    unsigned short* Wih1_b = (unsigned short*)(p + off); off += 2097152;
    unsigned short* Whh0_b = (unsigned short*)(p + off); off += 2097152;
    unsigned short* Whh1_b = (unsigned short*)(p + off); off += 2097152;
    unsigned short* pw0_b  = (unsigned short*)(p + off); off += 409600;
    unsigned short* pw1_b  = (unsigned short*)(p + off); off += 2621440;
    unsigned short* pw2_b  = (unsigned short*)(p + off); off += 2621440;
    unsigned short* pw3_b  = (unsigned short*)(p + off); off += 2621440;
    unsigned short* pw4_b  = (unsigned short*)(p + off); off += 409600;

    float* out_mel  = (float*)d_out;
    float* out_post = out_mel + (size_t)BT * M_;
    float* out_stop = out_post + (size_t)BT * M_;

    dim3 blk(256);
    auto MF = [&](const void* A, int lda, const float* mel, int srcC,
                  const unsigned short* Bt, void* C, int ldc, const float* bias,
                  int M, int N, int K, int mode, int abf16, int cbf16) {
        dim3 g((M + 127) / 128, (N + 127) / 128);
        k_mfma<<<g, blk, 0, stream>>>(A, lda, mel, srcC, Bt, C, ldc, bias, M, N, K, mode, abf16, cbf16);
    };

    // ---- prep
    k_prep<<<128, blk, 0, stream>>>(b_ih0, b_hh0, b_ih1, b_hh1, bsum0, bsum1,
                                    flags, (int*)hx2, ssum, ssq);
    k_weff<<<160, blk, 0, stream>>>(W_in, Wq, b_in, bq, Weff, beff);
    {
        dim3 gc(4736, 4);
        k_w_c4<<<gc, blk, 0, stream>>>(W_ih0, Wih0_b, G4 * DM,
                                       W_ih1, Wih1_b, G4 * D_,
                                       W_hh0, Whh0_b, G4 * D_,
                                       W_hh1, Whh1_b, G4 * D_);
        dim3 gt(1024, 4);
        k_w_t4<<<gt, blk, 0, stream>>>(Wk, Wk_t, D_, D_,
                                       Wv, Wv_t, D_, D_,
                                       Wo, Wo_t, D_, D_,
                                       W_mel, Wmel_t, D_, M_);
        dim3 gv(5120, 5);
        k_w_conv5<<<gv, blk, 0, stream>>>(pw0, pw0_b, 512, 80,
                                          pw1, pw1_b, 512, 512,
                                          pw2, pw2_b, 512, 512,
                                          pw3, pw3_b, 512, 512,
                                          pw4, pw4_b, 80, 512);
    }

    // ---- K/V projections
    MF(enc, D_, nullptr, 0, Wk_t, Kb, D_, bk, BS, D_, D_, 0, 0, 0);
    MF(enc, D_, nullptr, 0, Wv_t, Vb, D_, bv, BS, D_, D_, 0, 0, 0);

    // ---- attention
    k_attn<<<(B_ * H_ * T_) / 4, blk, 0, stream>>>(mel_t, Weff, beff, Kb, Vb, ctx);

    // ---- attn_out = ctx @ Wo + bo
    MF(ctx, D_, nullptr, 0, Wo_t, ao, D_, bo, BT, D_, D_, 0, 0, 0);

    // ---- xg0 (full T, bf16 out, virtual [ao | dec_in] concat, K=592)
    MF(ao, D_, mel_t, 0, Wih0_b, xg0, G4, bsum0, BT, G4, DM, 1, 0, 1);

    // ---- fused pipelined 2-layer LSTM (single launch)
    k_lstm2<<<NB_, blk, 0, stream>>>(xg0, Whh0_b, Wih1_b, Whh1_b, bsum1,
                                     hx1, hx2, h2seq, flags);

    // ---- heads
    MF(h2seq, D_, nullptr, 0, Wmel_t, out_mel, M_, b_mel, BT, M_, D_, 0, 1, 0);
    k_stop<<<BT / 4, blk, 0, stream>>>(h2seq, W_stop, b_stop, out_stop);

    // ---- postnet
    int gD = (BT * D_ + 255) / 256;

    MF(out_mel, 0, nullptr, M_, pw0_b, p_a, D_, pb0, BT, D_, M_ * 5, 2, 0, 0);
    k_stats_part<<<256, blk, 0, stream>>>(p_a, ssum, ssq);
    k_stats_fin<<<2, blk, 0, stream>>>(ssum, ssq, g0, be0, sc0, sh0);
    k_bnact<<<gD, blk, 0, stream>>>(p_a, D_, sc0, sh0);

    MF(p_a, 0, nullptr, D_, pw1_b, p_b, D_, pb1, BT, D_, D_ * 5, 2, 0, 0);
    k_stats_part<<<256, blk, 0, stream>>>(p_b, ssum, ssq);
    k_stats_fin<<<2, blk, 0, stream>>>(ssum, ssq, g1, be1, sc1, sh1);
    k_bnact<<<gD, blk, 0, stream>>>(p_b, D_, sc1, sh1);

    MF(p_b, 0, nullptr, D_, pw2_b, p_a, D_, pb2, BT, D_, D_ * 5, 2, 0, 0);
    k_stats_part<<<256, blk, 0, stream>>>(p_a, ssum, ssq);
    k_stats_fin<<<2, blk, 0, stream>>>(ssum, ssq, g2, be2, sc2, sh2);
    k_bnact<<<gD, blk, 0, stream>>>(p_a, D_, sc2, sh2);

    MF(p_a, 0, nullptr, D_, pw3_b, p_b, D_, pb3, BT, D_, D_ * 5, 2, 0, 0);
    k_stats_part<<<256, blk, 0, stream>>>(p_b, ssum, ssq);
    k_stats_fin<<<2, blk, 0, stream>>>(ssum, ssq, g3, be3, sc3, sh3);
    k_bnact<<<gD, blk, 0, stream>>>(p_b, D_, sc3, sh3);

    MF(p_b, 0, nullptr, D_, pw4_b, out_post, M_, pb4, BT, M_, D_ * 5, 2, 0, 0);
    k_residual<<<4000, blk, 0, stream>>>(out_mel, out_post);
}

// Round 12
// 4293.824 us; speedup vs baseline: 1.5510x; 1.5408x over previous
//
#include <hip/hip_runtime.h>
#include <math.h>

#define B_  32
#define S_  256
#define T_  400
#define M_  80
#define D_  512
#define H_  8
#define DH  64
#define BT  (B_*T_)    // 12800
#define BS  (B_*S_)    // 8192
#define G4  (4*D_)     // 2048
#define DM  (D_+M_)    // 592
#define NB_ 96         // persistent blocks: 32 L0 + 64 L1

typedef short s16x8 __attribute__((ext_vector_type(8)));
typedef float f32x4 __attribute__((ext_vector_type(4)));
typedef unsigned long long u64;

__device__ __forceinline__ unsigned short f2bf(float f) {
    union { float f; unsigned u; } v; v.f = f;
    unsigned r = v.u + 0x7fffu + ((v.u >> 16) & 1u);
    return (unsigned short)(r >> 16);
}
__device__ __forceinline__ float us2f(unsigned short u) {
    union { unsigned i; float f; } v; v.i = ((unsigned)u) << 16; return v.f;
}
__device__ __forceinline__ uint4 pack8(const float* f) {
    uint4 u;
    u.x = (unsigned)f2bf(f[0]) | ((unsigned)f2bf(f[1]) << 16);
    u.y = (unsigned)f2bf(f[2]) | ((unsigned)f2bf(f[3]) << 16);
    u.z = (unsigned)f2bf(f[4]) | ((unsigned)f2bf(f[5]) << 16);
    u.w = (unsigned)f2bf(f[6]) | ((unsigned)f2bf(f[7]) << 16);
    return u;
}
// coherent-point (sc1) exchange — cross-XCD visible without L2 fences
__device__ __forceinline__ u64 aload(const u64* p) {
    return __hip_atomic_load(p, __ATOMIC_RELAXED, __HIP_MEMORY_SCOPE_AGENT);
}
__device__ __forceinline__ void astore(u64* p, u64 v) {
    __hip_atomic_store(p, v, __ATOMIC_RELAXED, __HIP_MEMORY_SCOPE_AGENT);
}

// ---------------------------------------------------------------- prep
__global__ __launch_bounds__(256) void k_prep(
    const float* __restrict__ bih1, const float* __restrict__ bhh1,
    float* __restrict__ bsum1,
    int* __restrict__ flags, int* __restrict__ hx2i,
    float* __restrict__ ssum, float* __restrict__ ssq)
{
    int i = blockIdx.x * 256 + threadIdx.x;
    if (i < G4) bsum1[i] = bih1[i] + bhh1[i];
    if (i < 512) { ssum[i] = 0.f; ssq[i] = 0.f; }
    if (i < NB_ * 32) flags[i] = 0;          // spread: one flag per 128B line
    if (i < 2 * 32 * 512 / 2) hx2i[i] = 0;
}

// ---------------------------------------------------------------- batched weight prep
__global__ __launch_bounds__(256) void k_w_c4(
    const float* s0, unsigned short* d0p, int n0,
    const float* s1, unsigned short* d1p, int n1,
    const float* s2, unsigned short* d2p, int n2,
    const float* s3, unsigned short* d3p, int n3)
{
    const float* s; unsigned short* d; int n;
    switch (blockIdx.y) {
        case 0: s = s0; d = d0p; n = n0; break;
        case 1: s = s1; d = d1p; n = n1; break;
        case 2: s = s2; d = d2p; n = n2; break;
        default: s = s3; d = d3p; n = n3; break;
    }
    int i = blockIdx.x * 256 + threadIdx.x;
    if (i < n) d[i] = f2bf(s[i]);
}
// Wih0 permuted copy + permuted bias: dst row n' = bid*64 + g*16 + dl <- src row g*512 + bid*16 + dl
__global__ __launch_bounds__(256) void k_w_perm0(
    const float* __restrict__ W, unsigned short* __restrict__ dst,
    const float* __restrict__ bih, const float* __restrict__ bhh,
    float* __restrict__ bsum0p)
{
    int i = blockIdx.x * 256 + threadIdx.x;
    if (i < G4 * DM) {
        int np = i / DM, k = i - np * DM;
        int bd = np >> 6, r = np & 63, g = r >> 4, dl = r & 15;
        int ns = g * 512 + bd * 16 + dl;
        dst[i] = f2bf(W[(size_t)ns * DM + k]);
    }
    if (i < G4) {
        int bd = i >> 6, r = i & 63, g = r >> 4, dl = r & 15;
        int ns = g * 512 + bd * 16 + dl;
        bsum0p[i] = bih[ns] + bhh[ns];
    }
}
__global__ __launch_bounds__(256) void k_w_t4(
    const float* s0, unsigned short* d0p, int K0, int N0,
    const float* s1, unsigned short* d1p, int K1, int N1,
    const float* s2, unsigned short* d2p, int K2, int N2,
    const float* s3, unsigned short* d3p, int K3, int N3)
{
    const float* s; unsigned short* d; int K, N;
    switch (blockIdx.y) {
        case 0: s = s0; d = d0p; K = K0; N = N0; break;
        case 1: s = s1; d = d1p; K = K1; N = N1; break;
        case 2: s = s2; d = d2p; K = K2; N = N2; break;
        default: s = s3; d = d3p; K = K3; N = N3; break;
    }
    int i = blockIdx.x * 256 + threadIdx.x;
    if (i < K * N) {
        int n = i / K, k = i - n * K;
        d[i] = f2bf(s[(size_t)k * N + n]);
    }
}
__global__ __launch_bounds__(256) void k_w_conv5(
    const float* s0, unsigned short* d0p, int O0, int C0,
    const float* s1, unsigned short* d1p, int O1, int C1,
    const float* s2, unsigned short* d2p, int O2, int C2,
    const float* s3, unsigned short* d3p, int O3, int C3,
    const float* s4, unsigned short* d4p, int O4, int C4)
{
    const float* s; unsigned short* d; int O, C;
    switch (blockIdx.y) {
        case 0: s = s0; d = d0p; O = O0; C = C0; break;
        case 1: s = s1; d = d1p; O = O1; C = C1; break;
        case 2: s = s2; d = d2p; O = O2; C = C2; break;
        case 3: s = s3; d = d3p; O = O3; C = C3; break;
        default: s = s4; d = d4p; O = O4; C = C4; break;
    }
    int i = blockIdx.x * 256 + threadIdx.x;
    int n = O * C * 5;
    if (i < n) {
        int o = i / (5 * C), rem = i - o * 5 * C;
        int k = rem / C, c = rem - k * C;
        d[i] = f2bf(s[(size_t)o * C * 5 + c * 5 + k]);
    }
}

// ---------------------------------------------------------------- Weff = W_in@Wq, beff = b_in@Wq + bq
__global__ __launch_bounds__(256) void k_weff(
    const float* __restrict__ W_in, const float* __restrict__ Wq,
    const float* __restrict__ b_in, const float* __restrict__ bq,
    float* __restrict__ Weff, float* __restrict__ beff)
{
    int idx = blockIdx.x * 256 + threadIdx.x;
    if (idx < M_ * D_) {
        int m = idx / D_, d = idx - m * D_;
        float acc = 0.f;
        for (int j = 0; j < D_; ++j)
            acc += W_in[(size_t)m * D_ + j] * Wq[(size_t)j * D_ + d];
        Weff[idx] = acc;
    }
    if (idx < D_) {
        float acc = bq[idx];
        for (int j = 0; j < D_; ++j)
            acc += b_in[j] * Wq[(size_t)j * D_ + idx];
        beff[idx] = acc;
    }
}

// ---------------------------------------------------------------- MFMA GEMM
__global__ __launch_bounds__(256) void k_mfma(
    const void* __restrict__ Aptr, int lda, const float* __restrict__ mel, int srcC,
    const unsigned short* __restrict__ Bt,
    void* __restrict__ Cptr, int ldc, const float* __restrict__ bias,
    int M, int N, int K, int mode, int abf16, int cbf16)
{
    __shared__ unsigned short As[128][40];
    __shared__ unsigned short Bs[128][40];
    int tid = threadIdx.x;
    int m0 = blockIdx.x * 128, n0 = blockIdx.y * 128;
    int wave = tid >> 6, lane = tid & 63;
    int wm = (wave >> 1) * 64, wn = (wave & 1) * 64;
    int l15 = lane & 15, quad = lane >> 4;

    f32x4 acc[4][4] = {};

    int srow = tid >> 1, half = tid & 1;
    int arow = m0 + srow;
    bool mok = arow < M;
    int arc = mok ? arow : 0;

    const float* Af = (const float*)Aptr;
    const unsigned short* Ab = (const unsigned short*)Aptr;
    const float* Arow_f = nullptr; const unsigned short* Arow_b = nullptr;
    const float* Mrow = nullptr;
    int bA = 0, tA = 0;
    if (mode == 2) { bA = arc / T_; tA = arc - bA * T_; }
    else {
        if (abf16) Arow_b = Ab + (size_t)arc * lda;
        else       Arow_f = Af + (size_t)arc * lda;
        if (mode == 1) {
            int tt = arc % T_;
            if (tt > 0) Mrow = mel + (size_t)(arc - 1) * M_;
        }
    }
    int brow = n0 + srow;
    bool nok = brow < N;
    const unsigned short* Brow = Bt + (size_t)(nok ? brow : 0) * K;
    const uint4 z4 = make_uint4(0, 0, 0, 0);

    for (int k0 = 0; k0 < K; k0 += 32) {
        int ks = k0 + half * 16;
        uint4 a0, a1;
        if (!mok || ks >= K) { a0 = z4; a1 = z4; }
        else if (mode == 2) {
            int sg = ks / srcC;
            int cc = ks - sg * srcC;
            int tt = tA + sg - 2;
            if (tt >= 0 && tt < T_) {
                float tf[16];
                const float4* s = (const float4*)(Af + (size_t)(bA * T_ + tt) * srcC + cc);
                #pragma unroll
                for (int i = 0; i < 4; ++i) {
                    float4 v = s[i];
                    tf[i*4+0] = v.x; tf[i*4+1] = v.y; tf[i*4+2] = v.z; tf[i*4+3] = v.w;
                }
                a0 = pack8(tf); a1 = pack8(tf + 8);
            } else { a0 = z4; a1 = z4; }
        } else if (abf16) {
            const uint4* s = (const uint4*)(Arow_b + ks);
            a0 = s[0]; a1 = s[1];
        } else if (mode == 1 && ks >= D_) {
            if (Mrow) {
                float tf[16];
                const float4* s = (const float4*)(Mrow + (ks - D_));
                #pragma unroll
                for (int i = 0; i < 4; ++i) {
                    float4 v = s[i];
                    tf[i*4+0] = v.x; tf[i*4+1] = v.y; tf[i*4+2] = v.z; tf[i*4+3] = v.w;
                }
                a0 = pack8(tf); a1 = pack8(tf + 8);
            } else { a0 = z4; a1 = z4; }
        } else {
            float tf[16];
            const float4* s = (const float4*)(Arow_f + ks);
            #pragma unroll
            for (int i = 0; i < 4; ++i) {
                float4 v = s[i];
                tf[i*4+0] = v.x; tf[i*4+1] = v.y; tf[i*4+2] = v.z; tf[i*4+3] = v.w;
            }
            a0 = pack8(tf); a1 = pack8(tf + 8);
        }
        *(uint4*)&As[srow][half * 16]     = a0;
        *(uint4*)&As[srow][half * 16 + 8] = a1;

        uint4 b0, b1;
        if (!nok || ks >= K) { b0 = z4; b1 = z4; }
        else {
            const uint4* s = (const uint4*)(Brow + ks);
            b0 = s[0]; b1 = s[1];
        }
        *(uint4*)&Bs[srow][half * 16]     = b0;
        *(uint4*)&Bs[srow][half * 16 + 8] = b1;
        __syncthreads();

        s16x8 af[4], bfr[4];
        #pragma unroll
        for (int i = 0; i < 4; ++i)
            af[i] = *(const s16x8*)&As[wm + i * 16 + l15][quad * 8];
        #pragma unroll
        for (int j = 0; j < 4; ++j)
            bfr[j] = *(const s16x8*)&Bs[wn + j * 16 + l15][quad * 8];
        #pragma unroll
        for (int i = 0; i < 4; ++i)
            #pragma unroll
            for (int j = 0; j < 4; ++j)
                acc[i][j] = __builtin_amdgcn_mfma_f32_16x16x32_bf16(af[i], bfr[j], acc[i][j], 0, 0, 0);
        __syncthreads();
    }

    #pragma unroll
    for (int i = 0; i < 4; ++i) {
        #pragma unroll
        for (int j = 0; j < 4; ++j) {
            int col = n0 + wn + j * 16 + l15;
            if (col >= N) continue;
            float bv = bias ? bias[col] : 0.f;
            #pragma unroll
            for (int r = 0; r < 4; ++r) {
                int row = m0 + wm + i * 16 + quad * 4 + r;
                if (row >= M) continue;
                float v = acc[i][j][r] + bv;
                if (cbf16) ((unsigned short*)Cptr)[(size_t)row * ldc + col] = f2bf(v);
                else       ((float*)Cptr)[(size_t)row * ldc + col] = v;
            }
        }
    }
}

// ---------------------------------------------------------------- attention (fp32, q on the fly)
__global__ __launch_bounds__(256) void k_attn(
    const float* __restrict__ mel,
    const float* __restrict__ Weff, const float* __restrict__ beff,
    const float* __restrict__ Kb, const float* __restrict__ Vb,
    float* __restrict__ ctx)
{
    __shared__ float mrow[4][80];
    __shared__ float qs[4][64];
    __shared__ float ps[4][256];
    int w = threadIdx.x >> 6, lane = threadIdx.x & 63;
    int row = blockIdx.x * 4 + w;
    int t = row % T_; int bh = row / T_;
    int h = bh % H_;  int b = bh / H_;

    {
        float v = 0.f;
        if (t > 0) v = mel[(size_t)(b * T_ + (t - 1)) * M_ + lane];
        mrow[w][lane] = v;
        if (lane < 16) {
            float v2 = 0.f;
            if (t > 0) v2 = mel[(size_t)(b * T_ + (t - 1)) * M_ + 64 + lane];
            mrow[w][64 + lane] = v2;
        }
    }
    __syncthreads();
    {
        int d = h * DH + lane;
        float q = beff[d];
        #pragma unroll 8
        for (int m = 0; m < M_; ++m) q += mrow[w][m] * Weff[(size_t)m * D_ + d];
        qs[w][lane] = q;
    }
    __syncthreads();

    const float* Kbase = Kb + (size_t)(b * S_) * D_ + h * DH;
    float sc[4];
    #pragma unroll
    for (int i = 0; i < 4; ++i) {
        int s = lane + i * 64;
        const float4* kr = (const float4*)(Kbase + (size_t)s * D_);
        float acc = 0.f;
        #pragma unroll
        for (int c4 = 0; c4 < 16; ++c4) {
            float4 kv = kr[c4];
            acc += qs[w][c4 * 4 + 0] * kv.x + qs[w][c4 * 4 + 1] * kv.y
                 + qs[w][c4 * 4 + 2] * kv.z + qs[w][c4 * 4 + 3] * kv.w;
        }
        sc[i] = acc * 0.125f;
    }
    float mx = fmaxf(fmaxf(sc[0], sc[1]), fmaxf(sc[2], sc[3]));
    #pragma unroll
    for (int off = 32; off; off >>= 1) mx = fmaxf(mx, __shfl_xor(mx, off, 64));
    float sum = 0.f;
    #pragma unroll
    for (int i = 0; i < 4; ++i) { sc[i] = __expf(sc[i] - mx); sum += sc[i]; }
    #pragma unroll
    for (int off = 32; off; off >>= 1) sum += __shfl_xor(sum, off, 64);
    float inv = 1.f / sum;
    #pragma unroll
    for (int i = 0; i < 4; ++i) ps[w][lane + i * 64] = sc[i] * inv;
    __syncthreads();

    const float* Vbase = Vb + (size_t)(b * S_) * D_ + h * DH + lane;
    float acc = 0.f;
    for (int s = 0; s < S_; ++s) acc += ps[w][s] * Vbase[(size_t)s * D_];
    ctx[(size_t)(b * T_ + t) * D_ + h * DH + lane] = acc;
}

// ---------------------------------------------------------------- fused 2-layer pipelined LSTM
// R9 structure; h-exchange + flags via sc1 (agent-scope) atomics -> NO threadfences,
// L2 stays warm (xg/weights cached). xg0 is block-permuted: [bt][bid*64 + g*16 + dl].
__global__ __launch_bounds__(256) void k_lstm2(
    const unsigned short* __restrict__ xg0,
    const unsigned short* __restrict__ Whh0,
    const unsigned short* __restrict__ Wih1,
    const unsigned short* __restrict__ Whh1,
    const float* __restrict__ bsum1,
    unsigned short* __restrict__ hx1,         // [2][32*512]
    unsigned short* __restrict__ hx2,         // [2][32*512]
    unsigned short* __restrict__ h2seq,       // [B,T,512]
    int* __restrict__ flags)                  // [96*32] spread
{
    __shared__ char smem[137856];
    int tid = threadIdx.x;
    int bid = blockIdx.x;
    int lane = tid & 63, wv = tid >> 6;
    int l15 = lane & 15, quad = lane >> 4;

    if (bid < 32) {
        // =================== L0: 16 dims ===================
        unsigned short* Ws   = (unsigned short*)smem;              // [64][520]
        unsigned short* hs   = Ws + 64 * 520;                      // [32][520]
        float*          gl   = (float*)(smem + 99840);             // [64][33]
        unsigned short* hout = (unsigned short*)(smem + 108288);   // [32][16]
        int d0 = bid * 16;
        {
            int r = tid >> 2, seg = tid & 3;
            int g = r >> 4, d = r & 15;
            const uint4* src = (const uint4*)(Whh0 + ((size_t)(g * 512 + d0 + d) * 512) + seg * 128);
            uint4* dst = (uint4*)(Ws + r * 520 + seg * 128);
            #pragma unroll
            for (int j = 0; j < 16; ++j) dst[j] = src[j];
        }
        int b_u = tid >> 3, dp = tid & 7;
        float c0r = 0.f, c1r = 0.f;
        __syncthreads();

        for (int i = 0; i <= 400; ++i) {
            if (i < 400) {
                int t = i;
                unsigned xv[4];
                {   // permuted xg: 64 contiguous values per (b,t) for this block
                    const unsigned short* xr = xg0 + ((size_t)(b_u * T_ + t) * G4) + bid * 64;
                    #pragma unroll
                    for (int g = 0; g < 4; ++g) xv[g] = *(const unsigned*)(xr + g * 16 + 2 * dp);
                }
                if (t > 0) {
                    const u64* hrd = (const u64*)(hx1 + ((t + 1) & 1) * (32 * 512));
                    #pragma unroll
                    for (int it = 0; it < 8; ++it) {
                        int u = it * 256 + tid;
                        int row = u >> 6, c8 = u & 63;
                        u64 lo = aload(hrd + 2 * u);
                        u64 hi = aload(hrd + 2 * u + 1);
                        u64* d = (u64*)(hs + row * 520 + c8 * 8);
                        d[0] = lo; d[1] = hi;
                    }
                    __syncthreads();
                    f32x4 acc0 = {}, acc1 = {};
                    #pragma unroll
                    for (int k0 = 0; k0 < 512; k0 += 32) {
                        s16x8 af = *(const s16x8*)(Ws + (wv * 16 + l15) * 520 + k0 + quad * 8);
                        s16x8 b0 = *(const s16x8*)(hs + l15 * 520 + k0 + quad * 8);
                        s16x8 b1 = *(const s16x8*)(hs + (16 + l15) * 520 + k0 + quad * 8);
                        acc0 = __builtin_amdgcn_mfma_f32_16x16x32_bf16(af, b0, acc0, 0, 0, 0);
                        acc1 = __builtin_amdgcn_mfma_f32_16x16x32_bf16(af, b1, acc1, 0, 0, 0);
                    }
                    #pragma unroll
                    for (int r = 0; r < 4; ++r) {
                        gl[(wv * 16 + quad * 4 + r) * 33 + l15]      = acc0[r];
                        gl[(wv * 16 + quad * 4 + r) * 33 + 16 + l15] = acc1[r];
                    }
                }
                __syncthreads();
                {
                    float h2v[2];
                    #pragma unroll
                    for (int q = 0; q < 2; ++q) {
                        int d = 2 * dp + q;
                        float iv = us2f((unsigned short)(xv[0] >> (16 * q)));
                        float fv = us2f((unsigned short)(xv[1] >> (16 * q)));
                        float gv = us2f((unsigned short)(xv[2] >> (16 * q)));
                        float ov = us2f((unsigned short)(xv[3] >> (16 * q)));
                        if (t > 0) {
                            iv += gl[(0 * 16 + d) * 33 + b_u];
                            fv += gl[(1 * 16 + d) * 33 + b_u];
                            gv += gl[(2 * 16 + d) * 33 + b_u];
                            ov += gl[(3 * 16 + d) * 33 + b_u];
                        }
                        float si = 1.f / (1.f + __expf(-iv));
                        float sf = 1.f / (1.f + __expf(-fv));
                        float so = 1.f / (1.f + __expf(-ov));
                        float tg = tanhf(gv);
                        float cold = (t > 0) ? (q ? c1r : c0r) : 0.f;
                        float c = sf * cold + si * tg;
                        float h = so * tanhf(c);
                        if (q) c1r = c; else c0r = c;
                        h2v[q] = h;
                    }
                    unsigned pk = (unsigned)f2bf(h2v[0]) | ((unsigned)f2bf(h2v[1]) << 16);
                    *(unsigned*)(hout + b_u * 16 + 2 * dp) = pk;
                }
                __syncthreads();
                if (tid < 64) {
                    int b = tid >> 1, hf = tid & 1;
                    uint4 v = *(const uint4*)(hout + b * 16 + hf * 8);
                    u64 lo = ((u64)v.y << 32) | v.x;
                    u64 hi = ((u64)v.w << 32) | v.z;
                    u64* dst = (u64*)(hx1 + (t & 1) * (32 * 512) + (size_t)b * 512 + d0 + hf * 8);
                    astore(dst, lo); astore(dst + 1, hi);
                }
            }
            if (i < 400) {
                __syncthreads();   // drains sc1 stores (vmcnt0) before flag
                if (tid == 0)
                    __hip_atomic_store(flags + bid * 32, i + 1, __ATOMIC_RELAXED, __HIP_MEMORY_SCOPE_AGENT);
                if (tid < NB_) {
                    while (__hip_atomic_load(flags + tid * 32, __ATOMIC_RELAXED, __HIP_MEMORY_SCOPE_AGENT) < i + 1)
                        __builtin_amdgcn_s_sleep(1);
                }
                __syncthreads();
            }
        }
    } else {
        // =================== L1: 8 dims, fused K=1024 matvec ===================
        unsigned short* Wc    = (unsigned short*)smem;             // [32][1040]
        unsigned short* hcat  = Wc + 32 * 1040;                    // [32][1040]
        float*          gl1   = (float*)(smem + 133120);           // [32][33]
        unsigned short* hout1 = (unsigned short*)(smem + 137344);  // [32][8]
        int bd1 = bid - 32;
        int d0 = bd1 * 8;
        {
            int r = tid >> 3, seg = tid & 7;
            int g = r >> 3, d = r & 7;
            const unsigned short* wsrc = ((seg < 4) ? Wih1 : Whh1)
                + (size_t)(g * 512 + d0 + d) * 512 + (seg & 3) * 128;
            uint4* wdst = (uint4*)(Wc + r * 1040 + seg * 128);
            const uint4* ws4 = (const uint4*)wsrc;
            #pragma unroll
            for (int j = 0; j < 16; ++j) wdst[j] = ws4[j];
        }
        int dd = tid >> 5, b_u = tid & 31;
        float bs[4];
        #pragma unroll
        for (int g = 0; g < 4; ++g) bs[g] = bsum1[g * 512 + d0 + dd];
        int mt = wv >> 1, nt = wv & 1;
        float creg = 0.f;
        __syncthreads();

        for (int i = 0; i <= 400; ++i) {
            if (i >= 1) {
                int t = i - 1;
                const u64* s1 = (const u64*)(hx1 + ((i - 1) & 1) * (32 * 512));
                const u64* s2 = (const u64*)(hx2 + ((i - 2) & 1) * (32 * 512));
                #pragma unroll
                for (int it = 0; it < 8; ++it) {
                    int u = it * 256 + tid;
                    int row = u >> 6, c8 = u & 63;
                    u64 lo = aload(s1 + 2 * u), hi = aload(s1 + 2 * u + 1);
                    u64* d = (u64*)(hcat + row * 1040 + c8 * 8);
                    d[0] = lo; d[1] = hi;
                    lo = aload(s2 + 2 * u); hi = aload(s2 + 2 * u + 1);
                    d = (u64*)(hcat + row * 1040 + 512 + c8 * 8);
                    d[0] = lo; d[1] = hi;
                }
                __syncthreads();
                f32x4 acc = {};
                #pragma unroll 4
                for (int k0 = 0; k0 < 1024; k0 += 32) {
                    s16x8 af = *(const s16x8*)(Wc + (mt * 16 + l15) * 1040 + k0 + quad * 8);
                    s16x8 bf = *(const s16x8*)(hcat + (nt * 16 + l15) * 1040 + k0 + quad * 8);
                    acc = __builtin_amdgcn_mfma_f32_16x16x32_bf16(af, bf, acc, 0, 0, 0);
                }
                #pragma unroll
                for (int r = 0; r < 4; ++r)
                    gl1[(mt * 16 + quad * 4 + r) * 33 + nt * 16 + l15] = acc[r];
                __syncthreads();
                {
                    float iv = gl1[(0 * 8 + dd) * 33 + b_u] + bs[0];
                    float fv = gl1[(1 * 8 + dd) * 33 + b_u] + bs[1];
                    float gv = gl1[(2 * 8 + dd) * 33 + b_u] + bs[2];
                    float ov = gl1[(3 * 8 + dd) * 33 + b_u] + bs[3];
                    float si = 1.f / (1.f + __expf(-iv));
                    float sf = 1.f / (1.f + __expf(-fv));
                    float so = 1.f / (1.f + __expf(-ov));
                    float tg = tanhf(gv);
                    float cold = (t > 0) ? creg : 0.f;
                    float c = sf * cold + si * tg;
                    float h = so * tanhf(c);
                    creg = c;
                    hout1[b_u * 8 + dd] = f2bf(h);
                }
                __syncthreads();
                if (tid < 32) {
                    uint4 v = *(const uint4*)(hout1 + tid * 8);
                    u64 lo = ((u64)v.y << 32) | v.x;
                    u64 hi = ((u64)v.w << 32) | v.z;
                    u64* dst = (u64*)(hx2 + (t & 1) * (32 * 512) + (size_t)tid * 512 + d0);
                    astore(dst, lo); astore(dst + 1, hi);
                    *(uint4*)(h2seq + ((size_t)tid * T_ + t) * 512 + d0) = v;
                }
            }
            if (i < 400) {
                __syncthreads();
                if (tid == 0)
                    __hip_atomic_store(flags + bid * 32, i + 1, __ATOMIC_RELAXED, __HIP_MEMORY_SCOPE_AGENT);
                if (tid < NB_) {
                    while (__hip_atomic_load(flags + tid * 32, __ATOMIC_RELAXED, __HIP_MEMORY_SCOPE_AGENT) < i + 1)
                        __builtin_amdgcn_s_sleep(1);
                }
                __syncthreads();
            }
        }
    }
}

// ---------------------------------------------------------------- stop head
__global__ __launch_bounds__(256) void k_stop(
    const unsigned short* __restrict__ h2, const float* __restrict__ W,
    const float* __restrict__ bsc, float* __restrict__ out)
{
    int w = threadIdx.x >> 6, lane = threadIdx.x & 63;
    int row = blockIdx.x * 4 + w;
    const unsigned short* hr = h2 + (size_t)row * 512 + lane * 8;
    float acc = 0.f;
    #pragma unroll
    for (int j = 0; j < 8; ++j) acc += us2f(hr[j]) * W[lane * 8 + j];
    #pragma unroll
    for (int off = 32; off; off >>= 1) acc += __shfl_xor(acc, off, 64);
    if (lane == 0) out[row] = acc + bsc[0];
}

// ---------------------------------------------------------------- BN stats
__global__ __launch_bounds__(256) void k_stats_part(
    const float* __restrict__ x, float* __restrict__ ssum, float* __restrict__ ssq)
{
    int r0 = blockIdx.x * 50;
    int c1 = threadIdx.x, c2 = threadIdx.x + 256;
    float s1 = 0.f, q1 = 0.f, s2 = 0.f, q2 = 0.f;
    for (int r = r0; r < r0 + 50; ++r) {
        float v1 = x[(size_t)r * 512 + c1]; s1 += v1; q1 += v1 * v1;
        float v2 = x[(size_t)r * 512 + c2]; s2 += v2; q2 += v2 * v2;
    }
    atomicAdd(&ssum[c1], s1); atomicAdd(&ssq[c1], q1);
    atomicAdd(&ssum[c2], s2); atomicAdd(&ssq[c2], q2);
}
__global__ __launch_bounds__(256) void k_stats_fin(
    float* __restrict__ ssum, float* __restrict__ ssq,
    const float* __restrict__ gw, const float* __restrict__ bw,
    float* __restrict__ scale, float* __restrict__ shift)
{
    int c = blockIdx.x * 256 + threadIdx.x;
    if (c < 512) {
        float mean = ssum[c] / (float)BT;
        float var  = ssq[c] / (float)BT - mean * mean;
        float scv  = gw[c] * rsqrtf(var + 1e-5f);
        scale[c] = scv;
        shift[c] = bw[c] - mean * scv;
        ssum[c] = 0.f; ssq[c] = 0.f;
    }
}

__global__ __launch_bounds__(256) void k_bnact(
    float* __restrict__ x, int C,
    const float* __restrict__ scale, const float* __restrict__ shift)
{
    int idx = blockIdx.x * 256 + threadIdx.x;
    if (idx < BT * C) {
        int c = idx % C;
        x[idx] = tanhf(scale[c] * x[idx] + shift[c]);
    }
}

__global__ __launch_bounds__(256) void k_residual(
    const float* __restrict__ mel, float* __restrict__ out)
{
    int i = blockIdx.x * 256 + threadIdx.x;
    if (i < BT * M_) out[i] += mel[i];
}

// ================================================================ launch
extern "C" void kernel_launch(void* const* d_in, const int* in_sizes, int n_in,
                              void* d_out, int out_size, void* d_ws, size_t ws_size,
                              hipStream_t stream)
{
    const float* enc    = (const float*)d_in[0];
    const float* mel_t  = (const float*)d_in[1];
    const float* W_in   = (const float*)d_in[2];
    const float* b_in   = (const float*)d_in[3];
    const float* Wq     = (const float*)d_in[4];  const float* bq = (const float*)d_in[5];
    const float* Wk     = (const float*)d_in[6];  const float* bk = (const float*)d_in[7];
    const float* Wv     = (const float*)d_in[8];  const float* bv = (const float*)d_in[9];
    const float* Wo     = (const float*)d_in[10]; const float* bo = (const float*)d_in[11];
    const float* W_ih0  = (const float*)d_in[12]; const float* W_hh0 = (const float*)d_in[13];
    const float* b_ih0  = (const float*)d_in[14]; const float* b_hh0 = (const float*)d_in[15];
    const float* W_ih1  = (const float*)d_in[16]; const float* W_hh1 = (const float*)d_in[17];
    const float* b_ih1  = (const float*)d_in[18]; const float* b_hh1 = (const float*)d_in[19];
    const float* W_mel  = (const float*)d_in[20]; const float* b_mel = (const float*)d_in[21];
    const float* W_stop = (const float*)d_in[22]; const float* b_stop = (const float*)d_in[23];
    const float* pw0 = (const float*)d_in[24]; const float* pb0 = (const float*)d_in[25];
    const float* pw1 = (const float*)d_in[26]; const float* pb1 = (const float*)d_in[27];
    const float* pw2 = (const float*)d_in[28]; const float* pb2 = (const float*)d_in[29];
    const float* pw3 = (const float*)d_in[30]; const float* pb3 = (const float*)d_in[31];
    const float* pw4 = (const float*)d_in[32]; const float* pb4 = (const float*)d_in[33];
    const float* g0 = (const float*)d_in[34]; const float* be0 = (const float*)d_in[35];
    const float* g1 = (const float*)d_in[36]; const float* be1 = (const float*)d_in[37];
    const float* g2 = (const float*)d_in[38]; const float* be2 = (const float*)d_in[39];
    const float* g3 = (const float*)d_in[40]; const float* be3 = (const float*)d_in[41];

    char* p = (char*)d_ws;
    float* Kb  = (float*)(p + 0);
    float* Vb  = (float*)(p + 16777216);
    float* ctx = (float*)(p + 33554432);
    float* ao  = (float*)(p + 0);
    unsigned short* xg0   = (unsigned short*)(p + 26214400);
    unsigned short* h2seq = (unsigned short*)(p + 0);
    float* p_a = (float*)(p + 13107200);
    float* p_b = (float*)(p + 39321600);
    size_t off = 78643200;
    float* bsum0 = (float*)(p + off); off += 8192;   // permuted (k_w_perm0)
    float* bsum1 = (float*)(p + off); off += 8192;
    unsigned short* hx1 = (unsigned short*)(p + off); off += 65536;
    unsigned short* hx2 = (unsigned short*)(p + off); off += 65536;
    int* flags = (int*)(p + off); off += 12288;
    float* beff = (float*)(p + off); off += 2048;
    float* Weff = (float*)(p + off); off += 163840;
    float* sc0 = (float*)(p + off); off += 2048;
    float* sh0 = (float*)(p + off); off += 2048;
    float* sc1 = (float*)(p + off); off += 2048;
    float* sh1 = (float*)(p + off); off += 2048;
    float* sc2 = (float*)(p + off); off += 2048;
    float* sh2 = (float*)(p + off); off += 2048;
    float* sc3 = (float*)(p + off); off += 2048;
    float* sh3 = (float*)(p + off); off += 2048;
    float* ssum = (float*)(p + off); off += 2048;
    float* ssq  = (float*)(p + off); off += 2048;
    unsigned short* Wk_t   = (unsigned short*)(p + off); off += 524288;
    unsigned short* Wv_t   = (unsigned short*)(p + off); off += 524288;
    unsigned short* Wo_t   = (unsigned short*)(p + off); off += 524288;
    unsigned short* Wmel_t = (unsigned short*)(p + off); off += 81920;
    unsigned short* Wih0_b = (unsigned short*)(p + off); off += 2424832;
    unsigned short* Wih1_b = (unsigned short*)(p + off); off += 2097152;
    unsigned short* Whh0_b = (unsigned short*)(p + off); off += 2097152;
    unsigned short* Whh1_b = (unsigned short*)(p + off); off += 2097152;
    unsigned short* pw0_b  = (unsigned short*)(p + off); off += 409600;
    unsigned short* pw1_b  = (unsigned short*)(p + off); off += 2621440;
    unsigned short* pw2_b  = (unsigned short*)(p + off); off += 2621440;
    unsigned short* pw3_b  = (unsigned short*)(p + off); off += 2621440;
    unsigned short* pw4_b  = (unsigned short*)(p + off); off += 409600;

    float* out_mel  = (float*)d_out;
    float* out_post = out_mel + (size_t)BT * M_;
    float* out_stop = out_post + (size_t)BT * M_;

    dim3 blk(256);
    auto MF = [&](const void* A, int lda, const float* mel, int srcC,
                  const unsigned short* Bt, void* C, int ldc, const float* bias,
                  int M, int N, int K, int mode, int abf16, int cbf16) {
        dim3 g((M + 127) / 128, (N + 127) / 128);
        k_mfma<<<g, blk, 0, stream>>>(A, lda, mel, srcC, Bt, C, ldc, bias, M, N, K, mode, abf16, cbf16);
    };

    // ---- prep
    k_prep<<<128, blk, 0, stream>>>(b_ih1, b_hh1, bsum1, flags, (int*)hx2, ssum, ssq);
    k_weff<<<160, blk, 0, stream>>>(W_in, Wq, b_in, bq, Weff, beff);
    k_w_perm0<<<4736, blk, 0, stream>>>(W_ih0, Wih0_b, b_ih0, b_hh0, bsum0);
    {
        dim3 gc(4096, 4);
        k_w_c4<<<gc, blk, 0, stream>>>(W_ih1, Wih1_b, G4 * D_,
                                       W_hh0, Whh0_b, G4 * D_,
                                       W_hh1, Whh1_b, G4 * D_,
                                       W_ih1, Wih1_b, G4 * D_);
        dim3 gt(1024, 4);
        k_w_t4<<<gt, blk, 0, stream>>>(Wk, Wk_t, D_, D_,
                                       Wv, Wv_t, D_, D_,
                                       Wo, Wo_t, D_, D_,
                                       W_mel, Wmel_t, D_, M_);
        dim3 gv(5120, 5);
        k_w_conv5<<<gv, blk, 0, stream>>>(pw0, pw0_b, 512, 80,
                                          pw1, pw1_b, 512, 512,
                                          pw2, pw2_b, 512, 512,
                                          pw3, pw3_b, 512, 512,
                                          pw4, pw4_b, 80, 512);
    }

    // ---- K/V projections
    MF(enc, D_, nullptr, 0, Wk_t, Kb, D_, bk, BS, D_, D_, 0, 0, 0);
    MF(enc, D_, nullptr, 0, Wv_t, Vb, D_, bv, BS, D_, D_, 0, 0, 0);

    // ---- attention
    k_attn<<<(B_ * H_ * T_) / 4, blk, 0, stream>>>(mel_t, Weff, beff, Kb, Vb, ctx);

    // ---- attn_out = ctx @ Wo + bo
    MF(ctx, D_, nullptr, 0, Wo_t, ao, D_, bo, BT, D_, D_, 0, 0, 0);

    // ---- xg0 (block-permuted N; bf16 out; virtual [ao | dec_in] concat, K=592)
    MF(ao, D_, mel_t, 0, Wih0_b, xg0, G4, bsum0, BT, G4, DM, 1, 0, 1);

    // ---- fused pipelined 2-layer LSTM
    k_lstm2<<<NB_, blk, 0, stream>>>(xg0, Whh0_b, Wih1_b, Whh1_b, bsum1,
                                     hx1, hx2, h2seq, flags);

    // ---- heads
    MF(h2seq, D_, nullptr, 0, Wmel_t, out_mel, M_, b_mel, BT, M_, D_, 0, 1, 0);
    k_stop<<<BT / 4, blk, 0, stream>>>(h2seq, W_stop, b_stop, out_stop);

    // ---- postnet
    int gD = (BT * D_ + 255) / 256;

    MF(out_mel, 0, nullptr, M_, pw0_b, p_a, D_, pb0, BT, D_, M_ * 5, 2, 0, 0);
    k_stats_part<<<256, blk, 0, stream>>>(p_a, ssum, ssq);
    k_stats_fin<<<2, blk, 0, stream>>>(ssum, ssq, g0, be0, sc0, sh0);
    k_bnact<<<gD, blk, 0, stream>>>(p_a, D_, sc0, sh0);

    MF(p_a, 0, nullptr, D_, pw1_b, p_b, D_, pb1, BT, D_, D_ * 5, 2, 0, 0);
    k_stats_part<<<256, blk, 0, stream>>>(p_b, ssum, ssq);
    k_stats_fin<<<2, blk, 0, stream>>>(ssum, ssq, g1, be1, sc1, sh1);
    k_bnact<<<gD, blk, 0, stream>>>(p_b, D_, sc1, sh1);

    MF(p_b, 0, nullptr, D_, pw2_b, p_a, D_, pb2, BT, D_, D_ * 5, 2, 0, 0);
    k_stats_part<<<256, blk, 0, stream>>>(p_a, ssum, ssq);
    k_stats_fin<<<2, blk, 0, stream>>>(ssum, ssq, g2, be2, sc2, sh2);
    k_bnact<<<gD, blk, 0, stream>>>(p_a, D_, sc2, sh2);

    MF(p_a, 0, nullptr, D_, pw3_b, p_b, D_, pb3, BT, D_, D_ * 5, 2, 0, 0);
    k_stats_part<<<256, blk, 0, stream>>>(p_b, ssum, ssq);
    k_stats_fin<<<2, blk, 0, stream>>>(ssum, ssq, g3, be3, sc3, sh3);
    k_bnact<<<gD, blk, 0, stream>>>(p_b, D_, sc3, sh3);

    MF(p_b, 0, nullptr, D_, pw4_b, out_post, M_, pb4, BT, M_, D_ * 5, 2, 0, 0);
    k_residual<<<4000, blk, 0, stream>>>(out_mel, out_post);
}

// Round 13
// 3842.854 us; speedup vs baseline: 1.7330x; 1.1174x over previous
//
#include <hip/hip_runtime.h>
#include <math.h>

#define B_  32
#define S_  256
#define T_  400
#define M_  80
#define D_  512
#define H_  8
#define DH  64
#define BT  (B_*T_)    // 12800
#define BS  (B_*S_)    // 8192
#define G4  (4*D_)     // 2048
#define DM  (D_+M_)    // 592
#define NB_ 96         // persistent blocks: 32 L0 + 64 L1

typedef short s16x8 __attribute__((ext_vector_type(8)));
typedef float f32x4 __attribute__((ext_vector_type(4)));
typedef unsigned long long u64;

__device__ __forceinline__ unsigned short f2bf(float f) {
    union { float f; unsigned u; } v; v.f = f;
    unsigned r = v.u + 0x7fffu + ((v.u >> 16) & 1u);
    return (unsigned short)(r >> 16);
}
__device__ __forceinline__ float us2f(unsigned short u) {
    union { unsigned i; float f; } v; v.i = ((unsigned)u) << 16; return v.f;
}
__device__ __forceinline__ uint4 pack8(const float* f) {
    uint4 u;
    u.x = (unsigned)f2bf(f[0]) | ((unsigned)f2bf(f[1]) << 16);
    u.y = (unsigned)f2bf(f[2]) | ((unsigned)f2bf(f[3]) << 16);
    u.z = (unsigned)f2bf(f[4]) | ((unsigned)f2bf(f[5]) << 16);
    u.w = (unsigned)f2bf(f[6]) | ((unsigned)f2bf(f[7]) << 16);
    return u;
}
__device__ __forceinline__ void bf8_dec(const uint4 u, float* f) {
    f[0] = us2f(u.x & 0xffffu); f[1] = us2f(u.x >> 16);
    f[2] = us2f(u.y & 0xffffu); f[3] = us2f(u.y >> 16);
    f[4] = us2f(u.z & 0xffffu); f[5] = us2f(u.z >> 16);
    f[6] = us2f(u.w & 0xffffu); f[7] = us2f(u.w >> 16);
}
__device__ __forceinline__ u64 aload(const u64* p) {
    return __hip_atomic_load(p, __ATOMIC_RELAXED, __HIP_MEMORY_SCOPE_AGENT);
}
__device__ __forceinline__ void astore(u64* p, u64 v) {
    __hip_atomic_store(p, v, __ATOMIC_RELAXED, __HIP_MEMORY_SCOPE_AGENT);
}

// ---------------------------------------------------------------- prep
__global__ __launch_bounds__(256) void k_prep(
    const float* __restrict__ bih1, const float* __restrict__ bhh1,
    float* __restrict__ bsum1,
    int* __restrict__ flags, int* __restrict__ hx2i,
    float* __restrict__ ssum, float* __restrict__ ssq)
{
    int i = blockIdx.x * 256 + threadIdx.x;
    if (i < G4) bsum1[i] = bih1[i] + bhh1[i];
    if (i < 512) { ssum[i] = 0.f; ssq[i] = 0.f; }
    if (i < NB_ * 32) flags[i] = 0;          // spread: one flag per 128B line
    if (i < 2 * 32 * 512 / 2) hx2i[i] = 0;
}

// ---------------------------------------------------------------- batched weight prep
__global__ __launch_bounds__(256) void k_w_c4(
    const float* s0, unsigned short* d0p, int n0,
    const float* s1, unsigned short* d1p, int n1,
    const float* s2, unsigned short* d2p, int n2,
    const float* s3, unsigned short* d3p, int n3)
{
    const float* s; unsigned short* d; int n;
    switch (blockIdx.y) {
        case 0: s = s0; d = d0p; n = n0; break;
        case 1: s = s1; d = d1p; n = n1; break;
        case 2: s = s2; d = d2p; n = n2; break;
        default: s = s3; d = d3p; n = n3; break;
    }
    int i = blockIdx.x * 256 + threadIdx.x;
    if (i < n) d[i] = f2bf(s[i]);
}
// Wih0 permuted copy + permuted bias
__global__ __launch_bounds__(256) void k_w_perm0(
    const float* __restrict__ W, unsigned short* __restrict__ dst,
    const float* __restrict__ bih, const float* __restrict__ bhh,
    float* __restrict__ bsum0p)
{
    int i = blockIdx.x * 256 + threadIdx.x;
    if (i < G4 * DM) {
        int np = i / DM, k = i - np * DM;
        int bd = np >> 6, r = np & 63, g = r >> 4, dl = r & 15;
        int ns = g * 512 + bd * 16 + dl;
        dst[i] = f2bf(W[(size_t)ns * DM + k]);
    }
    if (i < G4) {
        int bd = i >> 6, r = i & 63, g = r >> 4, dl = r & 15;
        int ns = g * 512 + bd * 16 + dl;
        bsum0p[i] = bih[ns] + bhh[ns];
    }
}
__global__ __launch_bounds__(256) void k_w_t4(
    const float* s0, unsigned short* d0p, int K0, int N0,
    const float* s1, unsigned short* d1p, int K1, int N1,
    const float* s2, unsigned short* d2p, int K2, int N2,
    const float* s3, unsigned short* d3p, int K3, int N3)
{
    const float* s; unsigned short* d; int K, N;
    switch (blockIdx.y) {
        case 0: s = s0; d = d0p; K = K0; N = N0; break;
        case 1: s = s1; d = d1p; K = K1; N = N1; break;
        case 2: s = s2; d = d2p; K = K2; N = N2; break;
        default: s = s3; d = d3p; K = K3; N = N3; break;
    }
    int i = blockIdx.x * 256 + threadIdx.x;
    if (i < K * N) {
        int n = i / K, k = i - n * K;
        d[i] = f2bf(s[(size_t)k * N + n]);
    }
}
__global__ __launch_bounds__(256) void k_w_conv5(
    const float* s0, unsigned short* d0p, int O0, int C0,
    const float* s1, unsigned short* d1p, int O1, int C1,
    const float* s2, unsigned short* d2p, int O2, int C2,
    const float* s3, unsigned short* d3p, int O3, int C3,
    const float* s4, unsigned short* d4p, int O4, int C4)
{
    const float* s; unsigned short* d; int O, C;
    switch (blockIdx.y) {
        case 0: s = s0; d = d0p; O = O0; C = C0; break;
        case 1: s = s1; d = d1p; O = O1; C = C1; break;
        case 2: s = s2; d = d2p; O = O2; C = C2; break;
        case 3: s = s3; d = d3p; O = O3; C = C3; break;
        default: s = s4; d = d4p; O = O4; C = C4; break;
    }
    int i = blockIdx.x * 256 + threadIdx.x;
    int n = O * C * 5;
    if (i < n) {
        int o = i / (5 * C), rem = i - o * 5 * C;
        int k = rem / C, c = rem - k * C;
        d[i] = f2bf(s[(size_t)o * C * 5 + c * 5 + k]);
    }
}

// ---------------------------------------------------------------- Weff = W_in@Wq, beff = b_in@Wq + bq
__global__ __launch_bounds__(256) void k_weff(
    const float* __restrict__ W_in, const float* __restrict__ Wq,
    const float* __restrict__ b_in, const float* __restrict__ bq,
    float* __restrict__ Weff, float* __restrict__ beff)
{
    int idx = blockIdx.x * 256 + threadIdx.x;
    if (idx < M_ * D_) {
        int m = idx / D_, d = idx - m * D_;
        float acc = 0.f;
        for (int j = 0; j < D_; ++j)
            acc += W_in[(size_t)m * D_ + j] * Wq[(size_t)j * D_ + d];
        Weff[idx] = acc;
    }
    if (idx < D_) {
        float acc = bq[idx];
        for (int j = 0; j < D_; ++j)
            acc += b_in[j] * Wq[(size_t)j * D_ + idx];
        beff[idx] = acc;
    }
}

// ---------------------------------------------------------------- MFMA GEMM (+fused BN-stats / residual epilogue)
__global__ __launch_bounds__(256) void k_mfma(
    const void* __restrict__ Aptr, int lda, const float* __restrict__ mel, int srcC,
    const unsigned short* __restrict__ Bt,
    void* __restrict__ Cptr, int ldc, const float* __restrict__ bias,
    int M, int N, int K, int mode, int abf16, int cbf16,
    float* __restrict__ ssum_o, float* __restrict__ ssq_o,
    const float* __restrict__ resid)
{
    __shared__ unsigned short As[128][40];
    __shared__ unsigned short Bs[128][40];
    __shared__ float colsum[128];
    __shared__ float colsq[128];
    int tid = threadIdx.x;
    int m0 = blockIdx.x * 128, n0 = blockIdx.y * 128;
    int wave = tid >> 6, lane = tid & 63;
    int wm = (wave >> 1) * 64, wn = (wave & 1) * 64;
    int l15 = lane & 15, quad = lane >> 4;

    if (ssum_o && tid < 128) { colsum[tid] = 0.f; colsq[tid] = 0.f; }

    f32x4 acc[4][4] = {};

    int srow = tid >> 1, half = tid & 1;
    int arow = m0 + srow;
    bool mok = arow < M;
    int arc = mok ? arow : 0;

    const float* Af = (const float*)Aptr;
    const unsigned short* Ab = (const unsigned short*)Aptr;
    const float* Arow_f = nullptr; const unsigned short* Arow_b = nullptr;
    const float* Mrow = nullptr;
    int bA = 0, tA = 0;
    if (mode == 2) { bA = arc / T_; tA = arc - bA * T_; }
    else {
        if (abf16) Arow_b = Ab + (size_t)arc * lda;
        else       Arow_f = Af + (size_t)arc * lda;
        if (mode == 1) {
            int tt = arc % T_;
            if (tt > 0) Mrow = mel + (size_t)(arc - 1) * M_;
        }
    }
    int brow = n0 + srow;
    bool nok = brow < N;
    const unsigned short* Brow = Bt + (size_t)(nok ? brow : 0) * K;
    const uint4 z4 = make_uint4(0, 0, 0, 0);

    for (int k0 = 0; k0 < K; k0 += 32) {
        int ks = k0 + half * 16;
        uint4 a0, a1;
        if (!mok || ks >= K) { a0 = z4; a1 = z4; }
        else if (mode == 2) {
            int sg = ks / srcC;
            int cc = ks - sg * srcC;
            int tt = tA + sg - 2;
            if (tt >= 0 && tt < T_) {
                float tf[16];
                const float4* s = (const float4*)(Af + (size_t)(bA * T_ + tt) * srcC + cc);
                #pragma unroll
                for (int i = 0; i < 4; ++i) {
                    float4 v = s[i];
                    tf[i*4+0] = v.x; tf[i*4+1] = v.y; tf[i*4+2] = v.z; tf[i*4+3] = v.w;
                }
                a0 = pack8(tf); a1 = pack8(tf + 8);
            } else { a0 = z4; a1 = z4; }
        } else if (abf16) {
            const uint4* s = (const uint4*)(Arow_b + ks);
            a0 = s[0]; a1 = s[1];
        } else if (mode == 1 && ks >= D_) {
            if (Mrow) {
                float tf[16];
                const float4* s = (const float4*)(Mrow + (ks - D_));
                #pragma unroll
                for (int i = 0; i < 4; ++i) {
                    float4 v = s[i];
                    tf[i*4+0] = v.x; tf[i*4+1] = v.y; tf[i*4+2] = v.z; tf[i*4+3] = v.w;
                }
                a0 = pack8(tf); a1 = pack8(tf + 8);
            } else { a0 = z4; a1 = z4; }
        } else {
            float tf[16];
            const float4* s = (const float4*)(Arow_f + ks);
            #pragma unroll
            for (int i = 0; i < 4; ++i) {
                float4 v = s[i];
                tf[i*4+0] = v.x; tf[i*4+1] = v.y; tf[i*4+2] = v.z; tf[i*4+3] = v.w;
            }
            a0 = pack8(tf); a1 = pack8(tf + 8);
        }
        *(uint4*)&As[srow][half * 16]     = a0;
        *(uint4*)&As[srow][half * 16 + 8] = a1;

        uint4 b0, b1;
        if (!nok || ks >= K) { b0 = z4; b1 = z4; }
        else {
            const uint4* s = (const uint4*)(Brow + ks);
            b0 = s[0]; b1 = s[1];
        }
        *(uint4*)&Bs[srow][half * 16]     = b0;
        *(uint4*)&Bs[srow][half * 16 + 8] = b1;
        __syncthreads();

        s16x8 af[4], bfr[4];
        #pragma unroll
        for (int i = 0; i < 4; ++i)
            af[i] = *(const s16x8*)&As[wm + i * 16 + l15][quad * 8];
        #pragma unroll
        for (int j = 0; j < 4; ++j)
            bfr[j] = *(const s16x8*)&Bs[wn + j * 16 + l15][quad * 8];
        #pragma unroll
        for (int i = 0; i < 4; ++i)
            #pragma unroll
            for (int j = 0; j < 4; ++j)
                acc[i][j] = __builtin_amdgcn_mfma_f32_16x16x32_bf16(af[i], bfr[j], acc[i][j], 0, 0, 0);
        __syncthreads();
    }

    #pragma unroll
    for (int i = 0; i < 4; ++i) {
        #pragma unroll
        for (int j = 0; j < 4; ++j) {
            int col = n0 + wn + j * 16 + l15;
            if (col >= N) continue;
            float bv = bias ? bias[col] : 0.f;
            float s_acc = 0.f, q_acc = 0.f;
            #pragma unroll
            for (int r = 0; r < 4; ++r) {
                int row = m0 + wm + i * 16 + quad * 4 + r;
                if (row >= M) continue;
                float v = acc[i][j][r] + bv;
                if (resid) v += resid[(size_t)row * ldc + col];
                s_acc += v; q_acc += v * v;
                if (cbf16) ((unsigned short*)Cptr)[(size_t)row * ldc + col] = f2bf(v);
                else       ((float*)Cptr)[(size_t)row * ldc + col] = v;
            }
            if (ssum_o) {
                // reduce across quad (lanes l15, l15+16, l15+32, l15+48)
                s_acc += __shfl_xor(s_acc, 16, 64); s_acc += __shfl_xor(s_acc, 32, 64);
                q_acc += __shfl_xor(q_acc, 16, 64); q_acc += __shfl_xor(q_acc, 32, 64);
                if (quad == 0) {
                    atomicAdd(&colsum[wn + j * 16 + l15], s_acc);
                    atomicAdd(&colsq [wn + j * 16 + l15], q_acc);
                }
            }
        }
    }
    if (ssum_o) {
        __syncthreads();
        if (tid < 128) {
            int col = n0 + tid;
            if (col < N) {
                atomicAdd(&ssum_o[col], colsum[tid]);
                atomicAdd(&ssq_o[col],  colsq[tid]);
            }
        }
    }
}

// ---------------------------------------------------------------- attention (bf16 K/V, q on the fly, bf16 ctx)
__global__ __launch_bounds__(256) void k_attn(
    const float* __restrict__ mel,
    const float* __restrict__ Weff, const float* __restrict__ beff,
    const unsigned short* __restrict__ Kb, const unsigned short* __restrict__ Vb,
    unsigned short* __restrict__ ctx)
{
    __shared__ float mrow[4][80];
    __shared__ float qs[4][64];
    __shared__ float ps[4][256];
    int w = threadIdx.x >> 6, lane = threadIdx.x & 63;
    int row = blockIdx.x * 4 + w;
    int t = row % T_; int bh = row / T_;
    int h = bh % H_;  int b = bh / H_;

    {
        float v = 0.f;
        if (t > 0) v = mel[(size_t)(b * T_ + (t - 1)) * M_ + lane];
        mrow[w][lane] = v;
        if (lane < 16) {
            float v2 = 0.f;
            if (t > 0) v2 = mel[(size_t)(b * T_ + (t - 1)) * M_ + 64 + lane];
            mrow[w][64 + lane] = v2;
        }
    }
    __syncthreads();
    {
        int d = h * DH + lane;
        float q = beff[d];
        #pragma unroll 8
        for (int m = 0; m < M_; ++m) q += mrow[w][m] * Weff[(size_t)m * D_ + d];
        qs[w][lane] = q;
    }
    __syncthreads();

    const unsigned short* Kbase = Kb + (size_t)(b * S_) * D_ + h * DH;
    float sc[4];
    #pragma unroll
    for (int i = 0; i < 4; ++i) {
        int s = lane + i * 64;
        const uint4* kr = (const uint4*)(Kbase + (size_t)s * D_);
        float acc = 0.f;
        #pragma unroll
        for (int c8 = 0; c8 < 8; ++c8) {
            uint4 u = kr[c8];
            float kv[8]; bf8_dec(u, kv);
            #pragma unroll
            for (int j = 0; j < 8; ++j) acc += qs[w][c8 * 8 + j] * kv[j];
        }
        sc[i] = acc * 0.125f;
    }
    float mx = fmaxf(fmaxf(sc[0], sc[1]), fmaxf(sc[2], sc[3]));
    #pragma unroll
    for (int off = 32; off; off >>= 1) mx = fmaxf(mx, __shfl_xor(mx, off, 64));
    float sum = 0.f;
    #pragma unroll
    for (int i = 0; i < 4; ++i) { sc[i] = __expf(sc[i] - mx); sum += sc[i]; }
    #pragma unroll
    for (int off = 32; off; off >>= 1) sum += __shfl_xor(sum, off, 64);
    float inv = 1.f / sum;
    #pragma unroll
    for (int i = 0; i < 4; ++i) ps[w][lane + i * 64] = sc[i] * inv;
    __syncthreads();

    const unsigned short* Vbase = Vb + (size_t)(b * S_) * D_ + h * DH + lane;
    float acc = 0.f;
    for (int s = 0; s < S_; ++s) acc += ps[w][s] * us2f(Vbase[(size_t)s * D_]);
    ctx[(size_t)(b * T_ + t) * D_ + h * DH + lane] = f2bf(acc);
}

// ---------------------------------------------------------------- fused 2-layer pipelined LSTM (R12, unchanged)
__global__ __launch_bounds__(256) void k_lstm2(
    const unsigned short* __restrict__ xg0,
    const unsigned short* __restrict__ Whh0,
    const unsigned short* __restrict__ Wih1,
    const unsigned short* __restrict__ Whh1,
    const float* __restrict__ bsum1,
    unsigned short* __restrict__ hx1,
    unsigned short* __restrict__ hx2,
    unsigned short* __restrict__ h2seq,
    int* __restrict__ flags)
{
    __shared__ char smem[137856];
    int tid = threadIdx.x;
    int bid = blockIdx.x;
    int lane = tid & 63, wv = tid >> 6;
    int l15 = lane & 15, quad = lane >> 4;

    if (bid < 32) {
        unsigned short* Ws   = (unsigned short*)smem;
        unsigned short* hs   = Ws + 64 * 520;
        float*          gl   = (float*)(smem + 99840);
        unsigned short* hout = (unsigned short*)(smem + 108288);
        int d0 = bid * 16;
        {
            int r = tid >> 2, seg = tid & 3;
            int g = r >> 4, d = r & 15;
            const uint4* src = (const uint4*)(Whh0 + ((size_t)(g * 512 + d0 + d) * 512) + seg * 128);
            uint4* dst = (uint4*)(Ws + r * 520 + seg * 128);
            #pragma unroll
            for (int j = 0; j < 16; ++j) dst[j] = src[j];
        }
        int b_u = tid >> 3, dp = tid & 7;
        float c0r = 0.f, c1r = 0.f;
        __syncthreads();

        for (int i = 0; i <= 400; ++i) {
            if (i < 400) {
                int t = i;
                unsigned xv[4];
                {
                    const unsigned short* xr = xg0 + ((size_t)(b_u * T_ + t) * G4) + bid * 64;
                    #pragma unroll
                    for (int g = 0; g < 4; ++g) xv[g] = *(const unsigned*)(xr + g * 16 + 2 * dp);
                }
                if (t > 0) {
                    const u64* hrd = (const u64*)(hx1 + ((t + 1) & 1) * (32 * 512));
                    #pragma unroll
                    for (int it = 0; it < 8; ++it) {
                        int u = it * 256 + tid;
                        int row = u >> 6, c8 = u & 63;
                        u64 lo = aload(hrd + 2 * u);
                        u64 hi = aload(hrd + 2 * u + 1);
                        u64* d = (u64*)(hs + row * 520 + c8 * 8);
                        d[0] = lo; d[1] = hi;
                    }
                    __syncthreads();
                    f32x4 acc0 = {}, acc1 = {};
                    #pragma unroll
                    for (int k0 = 0; k0 < 512; k0 += 32) {
                        s16x8 af = *(const s16x8*)(Ws + (wv * 16 + l15) * 520 + k0 + quad * 8);
                        s16x8 b0 = *(const s16x8*)(hs + l15 * 520 + k0 + quad * 8);
                        s16x8 b1 = *(const s16x8*)(hs + (16 + l15) * 520 + k0 + quad * 8);
                        acc0 = __builtin_amdgcn_mfma_f32_16x16x32_bf16(af, b0, acc0, 0, 0, 0);
                        acc1 = __builtin_amdgcn_mfma_f32_16x16x32_bf16(af, b1, acc1, 0, 0, 0);
                    }
                    #pragma unroll
                    for (int r = 0; r < 4; ++r) {
                        gl[(wv * 16 + quad * 4 + r) * 33 + l15]      = acc0[r];
                        gl[(wv * 16 + quad * 4 + r) * 33 + 16 + l15] = acc1[r];
                    }
                }
                __syncthreads();
                {
                    float h2v[2];
                    #pragma unroll
                    for (int q = 0; q < 2; ++q) {
                        int d = 2 * dp + q;
                        float iv = us2f((unsigned short)(xv[0] >> (16 * q)));
                        float fv = us2f((unsigned short)(xv[1] >> (16 * q)));
                        float gv = us2f((unsigned short)(xv[2] >> (16 * q)));
                        float ov = us2f((unsigned short)(xv[3] >> (16 * q)));
                        if (t > 0) {
                            iv += gl[(0 * 16 + d) * 33 + b_u];
                            fv += gl[(1 * 16 + d) * 33 + b_u];
                            gv += gl[(2 * 16 + d) * 33 + b_u];
                            ov += gl[(3 * 16 + d) * 33 + b_u];
                        }
                        float si = 1.f / (1.f + __expf(-iv));
                        float sf = 1.f / (1.f + __expf(-fv));
                        float so = 1.f / (1.f + __expf(-ov));
                        float tg = tanhf(gv);
                        float cold = (t > 0) ? (q ? c1r : c0r) : 0.f;
                        float c = sf * cold + si * tg;
                        float h = so * tanhf(c);
                        if (q) c1r = c; else c0r = c;
                        h2v[q] = h;
                    }
                    unsigned pk = (unsigned)f2bf(h2v[0]) | ((unsigned)f2bf(h2v[1]) << 16);
                    *(unsigned*)(hout + b_u * 16 + 2 * dp) = pk;
                }
                __syncthreads();
                if (tid < 64) {
                    int b = tid >> 1, hf = tid & 1;
                    uint4 v = *(const uint4*)(hout + b * 16 + hf * 8);
                    u64 lo = ((u64)v.y << 32) | v.x;
                    u64 hi = ((u64)v.w << 32) | v.z;
                    u64* dst = (u64*)(hx1 + (t & 1) * (32 * 512) + (size_t)b * 512 + d0 + hf * 8);
                    astore(dst, lo); astore(dst + 1, hi);
                }
            }
            if (i < 400) {
                __syncthreads();
                if (tid == 0)
                    __hip_atomic_store(flags + bid * 32, i + 1, __ATOMIC_RELAXED, __HIP_MEMORY_SCOPE_AGENT);
                if (tid < NB_) {
                    while (__hip_atomic_load(flags + tid * 32, __ATOMIC_RELAXED, __HIP_MEMORY_SCOPE_AGENT) < i + 1)
                        __builtin_amdgcn_s_sleep(1);
                }
                __syncthreads();
            }
        }
    } else {
        unsigned short* Wc    = (unsigned short*)smem;
        unsigned short* hcat  = Wc + 32 * 1040;
        float*          gl1   = (float*)(smem + 133120);
        unsigned short* hout1 = (unsigned short*)(smem + 137344);
        int bd1 = bid - 32;
        int d0 = bd1 * 8;
        {
            int r = tid >> 3, seg = tid & 7;
            int g = r >> 3, d = r & 7;
            const unsigned short* wsrc = ((seg < 4) ? Wih1 : Whh1)
                + (size_t)(g * 512 + d0 + d) * 512 + (seg & 3) * 128;
            uint4* wdst = (uint4*)(Wc + r * 1040 + seg * 128);
            const uint4* ws4 = (const uint4*)wsrc;
            #pragma unroll
            for (int j = 0; j < 16; ++j) wdst[j] = ws4[j];
        }
        int dd = tid >> 5, b_u = tid & 31;
        float bs[4];
        #pragma unroll
        for (int g = 0; g < 4; ++g) bs[g] = bsum1[g * 512 + d0 + dd];
        int mt = wv >> 1, nt = wv & 1;
        float creg = 0.f;
        __syncthreads();

        for (int i = 0; i <= 400; ++i) {
            if (i >= 1) {
                int t = i - 1;
                const u64* s1 = (const u64*)(hx1 + ((i - 1) & 1) * (32 * 512));
                const u64* s2 = (const u64*)(hx2 + ((i - 2) & 1) * (32 * 512));
                #pragma unroll
                for (int it = 0; it < 8; ++it) {
                    int u = it * 256 + tid;
                    int row = u >> 6, c8 = u & 63;
                    u64 lo = aload(s1 + 2 * u), hi = aload(s1 + 2 * u + 1);
                    u64* d = (u64*)(hcat + row * 1040 + c8 * 8);
                    d[0] = lo; d[1] = hi;
                    lo = aload(s2 + 2 * u); hi = aload(s2 + 2 * u + 1);
                    d = (u64*)(hcat + row * 1040 + 512 + c8 * 8);
                    d[0] = lo; d[1] = hi;
                }
                __syncthreads();
                f32x4 acc = {};
                #pragma unroll 4
                for (int k0 = 0; k0 < 1024; k0 += 32) {
                    s16x8 af = *(const s16x8*)(Wc + (mt * 16 + l15) * 1040 + k0 + quad * 8);
                    s16x8 bf = *(const s16x8*)(hcat + (nt * 16 + l15) * 1040 + k0 + quad * 8);
                    acc = __builtin_amdgcn_mfma_f32_16x16x32_bf16(af, bf, acc, 0, 0, 0);
                }
                #pragma unroll
                for (int r = 0; r < 4; ++r)
                    gl1[(mt * 16 + quad * 4 + r) * 33 + nt * 16 + l15] = acc[r];
                __syncthreads();
                {
                    float iv = gl1[(0 * 8 + dd) * 33 + b_u] + bs[0];
                    float fv = gl1[(1 * 8 + dd) * 33 + b_u] + bs[1];
                    float gv = gl1[(2 * 8 + dd) * 33 + b_u] + bs[2];
                    float ov = gl1[(3 * 8 + dd) * 33 + b_u] + bs[3];
                    float si = 1.f / (1.f + __expf(-iv));
                    float sf = 1.f / (1.f + __expf(-fv));
                    float so = 1.f / (1.f + __expf(-ov));
                    float tg = tanhf(gv);
                    float cold = (t > 0) ? creg : 0.f;
                    float c = sf * cold + si * tg;
                    float h = so * tanhf(c);
                    creg = c;
                    hout1[b_u * 8 + dd] = f2bf(h);
                }
                __syncthreads();
                if (tid < 32) {
                    uint4 v = *(const uint4*)(hout1 + tid * 8);
                    u64 lo = ((u64)v.y << 32) | v.x;
                    u64 hi = ((u64)v.w << 32) | v.z;
                    u64* dst = (u64*)(hx2 + (t & 1) * (32 * 512) + (size_t)tid * 512 + d0);
                    astore(dst, lo); astore(dst + 1, hi);
                    *(uint4*)(h2seq + ((size_t)tid * T_ + t) * 512 + d0) = v;
                }
            }
            if (i < 400) {
                __syncthreads();
                if (tid == 0)
                    __hip_atomic_store(flags + bid * 32, i + 1, __ATOMIC_RELAXED, __HIP_MEMORY_SCOPE_AGENT);
                if (tid < NB_) {
                    while (__hip_atomic_load(flags + tid * 32, __ATOMIC_RELAXED, __HIP_MEMORY_SCOPE_AGENT) < i + 1)
                        __builtin_amdgcn_s_sleep(1);
                }
                __syncthreads();
            }
        }
    }
}

// ---------------------------------------------------------------- stop head
__global__ __launch_bounds__(256) void k_stop(
    const unsigned short* __restrict__ h2, const float* __restrict__ W,
    const float* __restrict__ bsc, float* __restrict__ out)
{
    int w = threadIdx.x >> 6, lane = threadIdx.x & 63;
    int row = blockIdx.x * 4 + w;
    const unsigned short* hr = h2 + (size_t)row * 512 + lane * 8;
    float acc = 0.f;
    #pragma unroll
    for (int j = 0; j < 8; ++j) acc += us2f(hr[j]) * W[lane * 8 + j];
    #pragma unroll
    for (int off = 32; off; off >>= 1) acc += __shfl_xor(acc, off, 64);
    if (lane == 0) out[row] = acc + bsc[0];
}

// ---------------------------------------------------------------- BN finalize (stats accumulated in conv epilogue)
__global__ __launch_bounds__(256) void k_stats_fin(
    float* __restrict__ ssum, float* __restrict__ ssq,
    const float* __restrict__ gw, const float* __restrict__ bw,
    float* __restrict__ scale, float* __restrict__ shift)
{
    int c = blockIdx.x * 256 + threadIdx.x;
    if (c < 512) {
        float mean = ssum[c] / (float)BT;
        float var  = ssq[c] / (float)BT - mean * mean;
        float scv  = gw[c] * rsqrtf(var + 1e-5f);
        scale[c] = scv;
        shift[c] = bw[c] - mean * scv;
        ssum[c] = 0.f; ssq[c] = 0.f;
    }
}

__global__ __launch_bounds__(256) void k_bnact(
    float* __restrict__ x, int C,
    const float* __restrict__ scale, const float* __restrict__ shift)
{
    int idx = blockIdx.x * 256 + threadIdx.x;
    if (idx < BT * C) {
        int c = idx % C;
        x[idx] = tanhf(scale[c] * x[idx] + shift[c]);
    }
}

// ================================================================ launch
extern "C" void kernel_launch(void* const* d_in, const int* in_sizes, int n_in,
                              void* d_out, int out_size, void* d_ws, size_t ws_size,
                              hipStream_t stream)
{
    const float* enc    = (const float*)d_in[0];
    const float* mel_t  = (const float*)d_in[1];
    const float* W_in   = (const float*)d_in[2];
    const float* b_in   = (const float*)d_in[3];
    const float* Wq     = (const float*)d_in[4];  const float* bq = (const float*)d_in[5];
    const float* Wk     = (const float*)d_in[6];  const float* bk = (const float*)d_in[7];
    const float* Wv     = (const float*)d_in[8];  const float* bv = (const float*)d_in[9];
    const float* Wo     = (const float*)d_in[10]; const float* bo = (const float*)d_in[11];
    const float* W_ih0  = (const float*)d_in[12]; const float* W_hh0 = (const float*)d_in[13];
    const float* b_ih0  = (const float*)d_in[14]; const float* b_hh0 = (const float*)d_in[15];
    const float* W_ih1  = (const float*)d_in[16]; const float* W_hh1 = (const float*)d_in[17];
    const float* b_ih1  = (const float*)d_in[18]; const float* b_hh1 = (const float*)d_in[19];
    const float* W_mel  = (const float*)d_in[20]; const float* b_mel = (const float*)d_in[21];
    const float* W_stop = (const float*)d_in[22]; const float* b_stop = (const float*)d_in[23];
    const float* pw0 = (const float*)d_in[24]; const float* pb0 = (const float*)d_in[25];
    const float* pw1 = (const float*)d_in[26]; const float* pb1 = (const float*)d_in[27];
    const float* pw2 = (const float*)d_in[28]; const float* pb2 = (const float*)d_in[29];
    const float* pw3 = (const float*)d_in[30]; const float* pb3 = (const float*)d_in[31];
    const float* pw4 = (const float*)d_in[32]; const float* pb4 = (const float*)d_in[33];
    const float* g0 = (const float*)d_in[34]; const float* be0 = (const float*)d_in[35];
    const float* g1 = (const float*)d_in[36]; const float* be1 = (const float*)d_in[37];
    const float* g2 = (const float*)d_in[38]; const float* be2 = (const float*)d_in[39];
    const float* g3 = (const float*)d_in[40]; const float* be3 = (const float*)d_in[41];

    char* p = (char*)d_ws;
    unsigned short* Kb  = (unsigned short*)(p + 0);           // bf16 now
    unsigned short* Vb  = (unsigned short*)(p + 16777216);    // bf16
    unsigned short* ctx = (unsigned short*)(p + 33554432);    // bf16
    float* ao  = (float*)(p + 0);
    unsigned short* xg0   = (unsigned short*)(p + 26214400);
    unsigned short* h2seq = (unsigned short*)(p + 0);
    float* p_a = (float*)(p + 13107200);
    float* p_b = (float*)(p + 39321600);
    size_t off = 78643200;
    float* bsum0 = (float*)(p + off); off += 8192;   // permuted
    float* bsum1 = (float*)(p + off); off += 8192;
    unsigned short* hx1 = (unsigned short*)(p + off); off += 65536;
    unsigned short* hx2 = (unsigned short*)(p + off); off += 65536;
    int* flags = (int*)(p + off); off += 12288;
    float* beff = (float*)(p + off); off += 2048;
    float* Weff = (float*)(p + off); off += 163840;
    float* sc0 = (float*)(p + off); off += 2048;
    float* sh0 = (float*)(p + off); off += 2048;
    float* sc1 = (float*)(p + off); off += 2048;
    float* sh1 = (float*)(p + off); off += 2048;
    float* sc2 = (float*)(p + off); off += 2048;
    float* sh2 = (float*)(p + off); off += 2048;
    float* sc3 = (float*)(p + off); off += 2048;
    float* sh3 = (float*)(p + off); off += 2048;
    float* ssum = (float*)(p + off); off += 2048;
    float* ssq  = (float*)(p + off); off += 2048;
    unsigned short* Wk_t   = (unsigned short*)(p + off); off += 524288;
    unsigned short* Wv_t   = (unsigned short*)(p + off); off += 524288;
    unsigned short* Wo_t   = (unsigned short*)(p + off); off += 524288;
    unsigned short* Wmel_t = (unsigned short*)(p + off); off += 81920;
    unsigned short* Wih0_b = (unsigned short*)(p + off); off += 2424832;
    unsigned short* Wih1_b = (unsigned short*)(p + off); off += 2097152;
    unsigned short* Whh0_b = (unsigned short*)(p + off); off += 2097152;
    unsigned short* Whh1_b = (unsigned short*)(p + off); off += 2097152;
    unsigned short* pw0_b  = (unsigned short*)(p + off); off += 409600;
    unsigned short* pw1_b  = (unsigned short*)(p + off); off += 2621440;
    unsigned short* pw2_b  = (unsigned short*)(p + off); off += 2621440;
    unsigned short* pw3_b  = (unsigned short*)(p + off); off += 2621440;
    unsigned short* pw4_b  = (unsigned short*)(p + off); off += 409600;

    float* out_mel  = (float*)d_out;
    float* out_post = out_mel + (size_t)BT * M_;
    float* out_stop = out_post + (size_t)BT * M_;

    dim3 blk(256);
    auto MF = [&](const void* A, int lda, const float* mel, int srcC,
                  const unsigned short* Bt, void* C, int ldc, const float* bias,
                  int M, int N, int K, int mode, int abf16, int cbf16,
                  float* so, float* sq, const float* rs) {
        dim3 g((M + 127) / 128, (N + 127) / 128);
        k_mfma<<<g, blk, 0, stream>>>(A, lda, mel, srcC, Bt, C, ldc, bias, M, N, K,
                                      mode, abf16, cbf16, so, sq, rs);
    };

    // ---- prep
    k_prep<<<128, blk, 0, stream>>>(b_ih1, b_hh1, bsum1, flags, (int*)hx2, ssum, ssq);
    k_weff<<<160, blk, 0, stream>>>(W_in, Wq, b_in, bq, Weff, beff);
    k_w_perm0<<<4736, blk, 0, stream>>>(W_ih0, Wih0_b, b_ih0, b_hh0, bsum0);
    {
        dim3 gc(4096, 4);
        k_w_c4<<<gc, blk, 0, stream>>>(W_ih1, Wih1_b, G4 * D_,
                                       W_hh0, Whh0_b, G4 * D_,
                                       W_hh1, Whh1_b, G4 * D_,
                                       W_ih1, Wih1_b, G4 * D_);
        dim3 gt(1024, 4);
        k_w_t4<<<gt, blk, 0, stream>>>(Wk, Wk_t, D_, D_,
                                       Wv, Wv_t, D_, D_,
                                       Wo, Wo_t, D_, D_,
                                       W_mel, Wmel_t, D_, M_);
        dim3 gv(5120, 5);
        k_w_conv5<<<gv, blk, 0, stream>>>(pw0, pw0_b, 512, 80,
                                          pw1, pw1_b, 512, 512,
                                          pw2, pw2_b, 512, 512,
                                          pw3, pw3_b, 512, 512,
                                          pw4, pw4_b, 80, 512);
    }

    // ---- K/V projections (bf16 out)
    MF(enc, D_, nullptr, 0, Wk_t, Kb, D_, bk, BS, D_, D_, 0, 0, 1, nullptr, nullptr, nullptr);
    MF(enc, D_, nullptr, 0, Wv_t, Vb, D_, bv, BS, D_, D_, 0, 0, 1, nullptr, nullptr, nullptr);

    // ---- attention (bf16 K/V, bf16 ctx)
    k_attn<<<(B_ * H_ * T_) / 4, blk, 0, stream>>>(mel_t, Weff, beff, Kb, Vb, ctx);

    // ---- attn_out = ctx @ Wo + bo (bf16 A)
    MF(ctx, D_, nullptr, 0, Wo_t, ao, D_, bo, BT, D_, D_, 0, 1, 0, nullptr, nullptr, nullptr);

    // ---- xg0 (block-permuted N; bf16 out; virtual [ao | dec_in] concat, K=592)
    MF(ao, D_, mel_t, 0, Wih0_b, xg0, G4, bsum0, BT, G4, DM, 1, 0, 1, nullptr, nullptr, nullptr);

    // ---- fused pipelined 2-layer LSTM
    k_lstm2<<<NB_, blk, 0, stream>>>(xg0, Whh0_b, Wih1_b, Whh1_b, bsum1,
                                     hx1, hx2, h2seq, flags);

    // ---- heads
    MF(h2seq, D_, nullptr, 0, Wmel_t, out_mel, M_, b_mel, BT, M_, D_, 0, 1, 0, nullptr, nullptr, nullptr);
    k_stop<<<BT / 4, blk, 0, stream>>>(h2seq, W_stop, b_stop, out_stop);

    // ---- postnet (BN stats fused into conv epilogue; residual fused into conv4)
    int gD = (BT * D_ + 255) / 256;

    MF(out_mel, 0, nullptr, M_, pw0_b, p_a, D_, pb0, BT, D_, M_ * 5, 2, 0, 0, ssum, ssq, nullptr);
    k_stats_fin<<<2, blk, 0, stream>>>(ssum, ssq, g0, be0, sc0, sh0);
    k_bnact<<<gD, blk, 0, stream>>>(p_a, D_, sc0, sh0);

    MF(p_a, 0, nullptr, D_, pw1_b, p_b, D_, pb1, BT, D_, D_ * 5, 2, 0, 0, ssum, ssq, nullptr);
    k_stats_fin<<<2, blk, 0, stream>>>(ssum, ssq, g1, be1, sc1, sh1);
    k_bnact<<<gD, blk, 0, stream>>>(p_b, D_, sc1, sh1);

    MF(p_b, 0, nullptr, D_, pw2_b, p_a, D_, pb2, BT, D_, D_ * 5, 2, 0, 0, ssum, ssq, nullptr);
    k_stats_fin<<<2, blk, 0, stream>>>(ssum, ssq, g2, be2, sc2, sh2);
    k_bnact<<<gD, blk, 0, stream>>>(p_a, D_, sc2, sh2);

    MF(p_a, 0, nullptr, D_, pw3_b, p_b, D_, pb3, BT, D_, D_ * 5, 2, 0, 0, ssum, ssq, nullptr);
    k_stats_fin<<<2, blk, 0, stream>>>(ssum, ssq, g3, be3, sc3, sh3);
    k_bnact<<<gD, blk, 0, stream>>>(p_b, D_, sc3, sh3);

    MF(p_b, 0, nullptr, D_, pw4_b, out_post, M_, pb4, BT, M_, D_ * 5, 2, 0, 0, nullptr, nullptr, out_mel);
}